// Round 14
// baseline (307.330 us; speedup 1.0000x reference)
//
#include <hip/hip_runtime.h>
#include <hip/hip_bf16.h>

// ---------------------------------------------------------------------------
// GraphSAGE 3-layer forward. bf16 MFMA GEMMs (f32 accum).
// R14 GEMM structure: register-resident B (no LDS -> zero bank conflicts,
// zero barriers), one strip x 64-col half per wave, ALL loads (32 B-frag +
// 8 A-frag) issued before first MFMA, __launch_bounds__(256,2) so the
// compiler keeps them in VGPRs (R6/R7 failed at VGPR=52: serialized VMEM;
// R13 failed on 8-way LDS bank conflicts). Both halves of a strip share a
// block for L1 A-reuse. No persistence.
//   layer0: H,H8 = relu(x@Wr0 + segmean8(x8)@Wl0 + b0)
//   layer1: Pb = H@Wr1 + segmean8(H8)@Wl1 + b1 (+f32 BN stats);
//           H = bf16(relu(BN(Pb)) + xb)
//   layer2: {A64 = H@Wl2, Tb = H@Wr2 + b2}; out = log_softmax(segmean(A64)+Tb)
// ---------------------------------------------------------------------------

#define WS_EPS 1e-5f

typedef unsigned short ushort_t;
typedef unsigned int uint_t;
typedef unsigned char uchar_t;
typedef ushort_t ushort8 __attribute__((ext_vector_type(8)));
typedef short short8 __attribute__((ext_vector_type(8)));
typedef float f32x4 __attribute__((ext_vector_type(4)));
typedef _Float16 half2v __attribute__((ext_vector_type(2)));

__device__ __forceinline__ float bf2f(ushort_t u) {
    return __uint_as_float(((uint_t)u) << 16);
}
__device__ __forceinline__ ushort_t f2bf(float f) {
    uint_t u = __float_as_uint(f);
    u = (u + 0x7fffu + ((u >> 16) & 1u)) >> 16;  // RNE
    return (ushort_t)u;
}
// f32 -> OCP e4m3fn with flush-to-zero of subnormals (decode = pure bit ops)
__device__ __forceinline__ uchar_t f2e4m3(float f) {
    _Float16 hf = (_Float16)f;  // RNE
    uint_t h = (uint_t)__builtin_bit_cast(unsigned short, hf);
    uint_t s = (h >> 8) & 0x80u;
    uint_t r = h & 0x7fffu;
    if (r < 0x2400u) return (uchar_t)0;   // |v| < 2^-6 -> 0
    if (r > 0x5F40u) r = 0x5F00u;         // clamp to 448
    uint_t u = r - 0x2000u;
    uint_t m = (u + 0x3fu + ((u >> 7) & 1u)) >> 7;  // RNE to 3-bit mantissa
    return (uchar_t)(s | m);
}

// ---- CSR build -------------------------------------------------------------
constexpr int SCHUNK = 4096;

__global__ __launch_bounds__(256) void k_scan_part(const int* __restrict__ deg,
                                                   int* __restrict__ bsum, int n) {
    int t = threadIdx.x;
    int base = blockIdx.x * SCHUNK + t * 16;
    int s = 0;
#pragma unroll
    for (int j = 0; j < 16; ++j) {
        int i = base + j;
        if (i < n) s += deg[i];
    }
#pragma unroll
    for (int d = 1; d < 64; d <<= 1) s += __shfl_xor(s, d);
    __shared__ int wt[4];
    if ((t & 63) == 0) wt[t >> 6] = s;
    __syncthreads();
    if (t == 0) bsum[blockIdx.x] = wt[0] + wt[1] + wt[2] + wt[3];
}

__global__ __launch_bounds__(64) void k_scan_bsum(const int* __restrict__ bsum,
                                                  int* __restrict__ boff,
                                                  int* __restrict__ off_n, int nb) {
    int lane = threadIdx.x;
    int carry = 0;
    for (int base = 0; base < nb; base += 64) {
        int t = base + lane;
        int v = (t < nb) ? bsum[t] : 0;
        int x = v;
#pragma unroll
        for (int d = 1; d < 64; d <<= 1) {
            int y = __shfl_up(x, d);
            if (lane >= d) x += y;
        }
        if (t < nb) boff[t] = carry + x - v;
        carry += __shfl(x, 63);
    }
    if (lane == 0) *off_n = carry;
}

__global__ __launch_bounds__(256) void k_scan_apply(const int* __restrict__ deg,
                                                    const int* __restrict__ boff,
                                                    int* __restrict__ off, int n) {
    int t = threadIdx.x;
    int lane = t & 63, wid = t >> 6;
    int base = blockIdx.x * SCHUNK + t * 16;
    int v[16];
    int s = 0;
#pragma unroll
    for (int j = 0; j < 16; ++j) {
        int i = base + j;
        v[j] = (i < n) ? deg[i] : 0;
        s += v[j];
    }
    int x = s;
#pragma unroll
    for (int d = 1; d < 64; d <<= 1) {
        int y = __shfl_up(x, d);
        if (lane >= d) x += y;
    }
    __shared__ int wtot[4];
    if (lane == 63) wtot[wid] = x;
    __syncthreads();
    int woff = 0;
    for (int wj = 0; wj < wid; ++wj) woff += wtot[wj];
    int run = boff[blockIdx.x] + woff + x - s;
#pragma unroll
    for (int j = 0; j < 16; ++j) {
        int i = base + j;
        if (i < n) off[i] = run;
        run += v[j];
    }
}

__global__ __launch_bounds__(256) void k_scatter(const int* __restrict__ ei,
                                                 const int* __restrict__ off,
                                                 int* __restrict__ cur,
                                                 int* __restrict__ csr, int E) {
    int e = blockIdx.x * 256 + threadIdx.x;
    if (e < E) {
        int d = ei[E + e];
        int s = ei[e];
        int p = atomicAdd(&cur[d], 1);
        csr[off[d] + p] = s;
    }
}

// ---- fused: degree count | x->bf16+fp8 | weights->bf16 transposed ----------
__global__ __launch_bounds__(256) void k_deg_prep(const int* __restrict__ ei,
                                                  int* __restrict__ deg, int E, int eb,
                                                  const float* __restrict__ x,
                                                  ushort_t* __restrict__ xb,
                                                  uchar_t* __restrict__ x8,
                                                  int total2, int nb_cvt,
                                                  const float* __restrict__ Wl0,
                                                  const float* __restrict__ Wr0,
                                                  const float* __restrict__ Wl1,
                                                  const float* __restrict__ Wr1,
                                                  const float* __restrict__ Wl2,
                                                  const float* __restrict__ Wr2,
                                                  ushort_t* __restrict__ wts) {
    int b = blockIdx.x;
    if (b < eb) {
        int e = b * 256 + threadIdx.x;
        if (e < E) atomicAdd(&deg[ei[E + e]], 1);
        return;
    }
    b -= eb;
    if (b < nb_cvt) {
        int i = b * 256 + threadIdx.x;
        if (i >= total2) return;
        float2 v = *(const float2*)&x[(size_t)i * 2];
        uint_t p = (uint_t)f2bf(v.x) | ((uint_t)f2bf(v.y) << 16);
        *(uint_t*)&xb[(size_t)i * 2] = p;
        ushort_t q = (ushort_t)((uint_t)f2e4m3(v.x) | ((uint_t)f2e4m3(v.y) << 8));
        *(ushort_t*)&x8[(size_t)i * 2] = q;
        return;
    }
    int id = (b - nb_cvt) * 256 + threadIdx.x;
    if (id >= 81920) return;
    const float* W;
    int rel, nout, base;
    if (id < 65536) {
        int m = id >> 14;
        rel = id & 16383;
        nout = 128;
        base = m << 14;
        W = (m == 0) ? Wl0 : (m == 1) ? Wr0 : (m == 2) ? Wl1 : Wr1;
    } else {
        int m = (id - 65536) >> 13;
        rel = (id - 65536) & 8191;
        nout = 64;
        base = 65536 + (m << 13);
        W = (m == 0) ? Wl2 : Wr2;
    }
    int c = rel >> 7;
    int k = rel & 127;
    wts[base + rel] = f2bf(W[(size_t)k * nout + c]);
}

// ---- dual GEMM: reg-B, one strip x 64-col half per wave, no LDS ------------
// out[n][128] = X1@W1 + X2@W2 + bias. Waves 2w/2w+1 of a block share strip
// (L1 A-reuse). All 40 loads issued before first MFMA.
// EPI: 2 -> relu, bf16 out + fp8 out8 (layer 0); 1 -> bf16 out + BN stats.
template <int EPI>
__global__ __launch_bounds__(256, 2) void k_dgemm(const ushort_t* __restrict__ X1,
                                                  const ushort_t* __restrict__ W1,
                                                  const ushort_t* __restrict__ X2,
                                                  const ushort_t* __restrict__ W2,
                                                  const float* __restrict__ bias,
                                                  ushort_t* __restrict__ outp,
                                                  uchar_t* __restrict__ out8,
                                                  float* __restrict__ stats, int n) {
    constexpr int K = 128, NOUT = 128;
    const int t = threadIdx.x;
    const int lane = t & 63;
    const int r16 = lane & 15, kb = lane >> 4;
    const int w = t >> 6;
    const int strip = blockIdx.x * 2 + (w >> 1);
    const int colbase = (w & 1) * 64;
    const int strips = (n + 15) >> 4;
    if (strip >= strips) return;

    // B-fragments: 32 independent loads (L2-hot 32KB tables)
    short8 B1[4][4], B2[4][4];
#pragma unroll
    for (int fn = 0; fn < 4; ++fn)
#pragma unroll
        for (int ks = 0; ks < 4; ++ks)
            B1[fn][ks] = *(const short8*)&W1[(size_t)(colbase + fn * 16 + r16) * K + ks * 32 + kb * 8];
#pragma unroll
    for (int fn = 0; fn < 4; ++fn)
#pragma unroll
        for (int ks = 0; ks < 4; ++ks)
            B2[fn][ks] = *(const short8*)&W2[(size_t)(colbase + fn * 16 + r16) * K + ks * 32 + kb * 8];

    // A-fragments: 8 loads
    const int arow = strip * 16 + r16;
    const bool rok = (arow < n);
    const size_t xo = (size_t)arow * K + kb * 8;
    short8 a1[4], a2[4];
#pragma unroll
    for (int ks = 0; ks < 4; ++ks)
        a1[ks] = rok ? *(const short8*)&X1[xo + ks * 32] : (short8)0;
#pragma unroll
    for (int ks = 0; ks < 4; ++ks)
        a2[ks] = rok ? *(const short8*)&X2[xo + ks * 32] : (short8)0;

    f32x4 acc[4] = {(f32x4)0.f, (f32x4)0.f, (f32x4)0.f, (f32x4)0.f};
#pragma unroll
    for (int ks = 0; ks < 4; ++ks)
#pragma unroll
        for (int fn = 0; fn < 4; ++fn)
            acc[fn] = __builtin_amdgcn_mfma_f32_16x16x32_bf16(a1[ks], B1[fn][ks], acc[fn], 0, 0, 0);
#pragma unroll
    for (int ks = 0; ks < 4; ++ks)
#pragma unroll
        for (int fn = 0; fn < 4; ++fn)
            acc[fn] = __builtin_amdgcn_mfma_f32_16x16x32_bf16(a2[ks], B2[fn][ks], acc[fn], 0, 0, 0);

    float bcol[4];
#pragma unroll
    for (int fn = 0; fn < 4; ++fn) bcol[fn] = bias[colbase + fn * 16 + r16];

    if constexpr (EPI == 2) {
        const int rb = strip * 16 + kb * 4;
#pragma unroll
        for (int r = 0; r < 4; ++r) {
            int row = rb + r;
            if (row >= n) continue;
#pragma unroll
            for (int fn = 0; fn < 4; ++fn) {
                int col = colbase + fn * 16 + r16;
                float v = fmaxf(acc[fn][r] + bcol[fn], 0.f);
                outp[(size_t)row * NOUT + col] = f2bf(v);
                out8[(size_t)row * NOUT + col] = f2e4m3(v);
            }
        }
    } else {
        float ssum[4] = {0.f, 0.f, 0.f, 0.f}, qsum[4] = {0.f, 0.f, 0.f, 0.f};
        const int rb = strip * 16 + kb * 4;
#pragma unroll
        for (int r = 0; r < 4; ++r) {
            int row = rb + r;
            if (row >= n) continue;
#pragma unroll
            for (int fn = 0; fn < 4; ++fn) {
                int col = colbase + fn * 16 + r16;
                float v = acc[fn][r] + bcol[fn];
                outp[(size_t)row * NOUT + col] = f2bf(v);
                ssum[fn] += v;
                qsum[fn] += v * v;
            }
        }
#pragma unroll
        for (int fn = 0; fn < 4; ++fn) {
            ssum[fn] += __shfl_xor(ssum[fn], 16);
            ssum[fn] += __shfl_xor(ssum[fn], 32);
            qsum[fn] += __shfl_xor(qsum[fn], 16);
            qsum[fn] += __shfl_xor(qsum[fn], 32);
        }
        if (kb == 0) {
#pragma unroll
            for (int fn = 0; fn < 4; ++fn) {
                int col = colbase + fn * 16 + r16;
                atomicAdd(&stats[col], ssum[fn]);
                atomicAdd(&stats[128 + col], qsum[fn]);
            }
        }
    }
}

// ---- layer-2 GEMM: reg-B, one strip per wave, both outputs -----------------
// A64 = H@Wl2 (bf16), Tb = H@Wr2 + b2 (bf16). 36 loads before first MFMA.
__global__ __launch_bounds__(256, 2) void k_cgemm(const ushort_t* __restrict__ H,
                                                  const ushort_t* __restrict__ WL,
                                                  const ushort_t* __restrict__ WR,
                                                  const float* __restrict__ b2,
                                                  ushort_t* __restrict__ A64,
                                                  ushort_t* __restrict__ Tb, int n) {
    constexpr int K = 128;
    const int t = threadIdx.x;
    const int lane = t & 63;
    const int r16 = lane & 15, kb = lane >> 4;
    const int strip = blockIdx.x * 4 + (t >> 6);
    const int strips = (n + 15) >> 4;
    if (strip >= strips) return;

    short8 BL[4][4], BR[4][4];
#pragma unroll
    for (int fn = 0; fn < 4; ++fn)
#pragma unroll
        for (int ks = 0; ks < 4; ++ks)
            BL[fn][ks] = *(const short8*)&WL[(size_t)(fn * 16 + r16) * K + ks * 32 + kb * 8];
#pragma unroll
    for (int fn = 0; fn < 4; ++fn)
#pragma unroll
        for (int ks = 0; ks < 4; ++ks)
            BR[fn][ks] = *(const short8*)&WR[(size_t)(fn * 16 + r16) * K + ks * 32 + kb * 8];

    const int arow = strip * 16 + r16;
    const bool rok = (arow < n);
    const size_t xo = (size_t)arow * K + kb * 8;
    short8 a[4];
#pragma unroll
    for (int ks = 0; ks < 4; ++ks)
        a[ks] = rok ? *(const short8*)&H[xo + ks * 32] : (short8)0;

    f32x4 aL[4] = {(f32x4)0.f, (f32x4)0.f, (f32x4)0.f, (f32x4)0.f};
    f32x4 aR[4] = {(f32x4)0.f, (f32x4)0.f, (f32x4)0.f, (f32x4)0.f};
#pragma unroll
    for (int ks = 0; ks < 4; ++ks)
#pragma unroll
        for (int fn = 0; fn < 4; ++fn) {
            aL[fn] = __builtin_amdgcn_mfma_f32_16x16x32_bf16(a[ks], BL[fn][ks], aL[fn], 0, 0, 0);
            aR[fn] = __builtin_amdgcn_mfma_f32_16x16x32_bf16(a[ks], BR[fn][ks], aR[fn], 0, 0, 0);
        }

    float bcol[4];
#pragma unroll
    for (int fn = 0; fn < 4; ++fn) bcol[fn] = b2[fn * 16 + r16];

    const int rb = strip * 16 + kb * 4;
#pragma unroll
    for (int r = 0; r < 4; ++r) {
        int row = rb + r;
        if (row >= n) continue;
#pragma unroll
        for (int fn = 0; fn < 4; ++fn) {
            int col = fn * 16 + r16;
            A64[(size_t)row * 64 + col] = f2bf(aL[fn][r]);
            Tb[(size_t)row * 64 + col] = f2bf(aR[fn][r] + bcol[fn]);
        }
    }
}

// ---- segment mean over CSR, fp8 in -> bf16 out. 8 lanes/node, 16 ch/lane ---
__global__ __launch_bounds__(256) void k_segmean8(const uchar_t* __restrict__ U8,
                                                  const int* __restrict__ off,
                                                  const int* __restrict__ srcs,
                                                  ushort_t* __restrict__ out, int n) {
    int node = blockIdx.x * 32 + (threadIdx.x >> 3);
    int sub = threadIdx.x & 7;
    if (node >= n) return;
    int beg = off[node], end = off[node + 1];
    half2v aE0 = (half2v)0, aE1 = (half2v)0, aE2 = (half2v)0, aE3 = (half2v)0;
    half2v aO0 = (half2v)0, aO1 = (half2v)0, aO2 = (half2v)0, aO3 = (half2v)0;

#define DEC(dw, AE, AO)                                                           \
    {                                                                             \
        uint_t xe = (dw)&0x00ff00ffu;                                             \
        uint_t xo = ((dw) >> 8) & 0x00ff00ffu;                                    \
        uint_t he = ((xe & 0x00800080u) << 8) |                                   \
                    (((xe & 0x007f007fu) << 7) + 0x20002000u);                    \
        uint_t ho = ((xo & 0x00800080u) << 8) |                                   \
                    (((xo & 0x007f007fu) << 7) + 0x20002000u);                    \
        AE += __builtin_bit_cast(half2v, he);                                     \
        AO += __builtin_bit_cast(half2v, ho);                                     \
    }

    auto addrow = [&](int sidx) {
        uint4 v = *(const uint4*)&U8[(size_t)sidx * 128 + sub * 16];
        DEC(v.x, aE0, aO0)
        DEC(v.y, aE1, aO1)
        DEC(v.z, aE2, aO2)
        DEC(v.w, aE3, aO3)
    };
#undef DEC

    int i = beg;
    for (; i + 8 <= end; i += 8) {
        int sv[8];
#pragma unroll
        for (int u = 0; u < 8; ++u) sv[u] = srcs[i + u];
#pragma unroll
        for (int u = 0; u < 8; ++u) addrow(sv[u]);
    }
    for (; i < end; ++i) addrow(srcs[i]);

    int d = end - beg;
    float inv = 1.f / (float)(d > 1 ? d : 1);
    ushort8 o0, o1;
#define PACK(AE, AO, O, IDX)                     \
    O[IDX] = f2bf((float)AE[0] * inv);           \
    O[IDX + 1] = f2bf((float)AO[0] * inv);       \
    O[IDX + 2] = f2bf((float)AE[1] * inv);       \
    O[IDX + 3] = f2bf((float)AO[1] * inv);
    PACK(aE0, aO0, o0, 0)
    PACK(aE1, aO1, o0, 4)
    PACK(aE2, aO2, o1, 0)
    PACK(aE3, aO3, o1, 4)
#undef PACK
    *(ushort8*)&out[(size_t)node * 128 + sub * 16] = o0;
    *(ushort8*)&out[(size_t)node * 128 + sub * 16 + 8] = o1;
}

// ---- fused 64-d segmean + log_softmax: out = lsm(segmean(A64) + Tb) --------
__global__ __launch_bounds__(256) void k_segmean_lsm(const ushort_t* __restrict__ A64,
                                                     const int* __restrict__ off,
                                                     const int* __restrict__ srcs,
                                                     const ushort_t* __restrict__ Tb,
                                                     float* __restrict__ out, int n) {
    int node = blockIdx.x * 32 + (threadIdx.x >> 3);
    int sub = threadIdx.x & 7;
    if (node >= n) return;
    int beg = off[node], end = off[node + 1];
    float a[8];
#pragma unroll
    for (int j = 0; j < 8; ++j) a[j] = 0.f;
    int i = beg;
    for (; i + 8 <= end; i += 8) {
        int sv[8];
#pragma unroll
        for (int u = 0; u < 8; ++u) sv[u] = srcs[i + u];
#pragma unroll
        for (int u = 0; u < 8; ++u) {
            ushort8 v = *(const ushort8*)&A64[(size_t)sv[u] * 64 + sub * 8];
#pragma unroll
            for (int j = 0; j < 8; ++j) a[j] += bf2f((ushort_t)v[j]);
        }
    }
    for (; i < end; ++i) {
        ushort8 v = *(const ushort8*)&A64[(size_t)srcs[i] * 64 + sub * 8];
#pragma unroll
        for (int j = 0; j < 8; ++j) a[j] += bf2f((ushort_t)v[j]);
    }
    int d = end - beg;
    float inv = 1.f / (float)(d > 1 ? d : 1);
    ushort8 tv = *(const ushort8*)&Tb[(size_t)node * 64 + sub * 8];
    float vv[8];
#pragma unroll
    for (int j = 0; j < 8; ++j) vv[j] = a[j] * inv + bf2f((ushort_t)tv[j]);
    float m = vv[0];
#pragma unroll
    for (int j = 1; j < 8; ++j) m = fmaxf(m, vv[j]);
#pragma unroll
    for (int dd = 1; dd < 8; dd <<= 1) m = fmaxf(m, __shfl_xor(m, dd));
    float e = 0.f;
#pragma unroll
    for (int j = 0; j < 8; ++j) e += expf(vv[j] - m);
#pragma unroll
    for (int dd = 1; dd < 8; dd <<= 1) e += __shfl_xor(e, dd);
    float lg = m + logf(e);
    f32x4 o0, o1;
#pragma unroll
    for (int j = 0; j < 4; ++j) {
        o0[j] = vv[j] - lg;
        o1[j] = vv[4 + j] - lg;
    }
    *(f32x4*)&out[(size_t)node * 64 + sub * 8] = o0;
    *(f32x4*)&out[(size_t)node * 64 + sub * 8 + 4] = o1;
}

// ---- BN apply + relu + residual (xb bf16), Pb bf16 -> H bf16 ---------------
__global__ __launch_bounds__(256) void k_bnapply(const ushort_t* __restrict__ P,
                                                 const ushort_t* __restrict__ Xb,
                                                 const float* __restrict__ stats,
                                                 const float* __restrict__ gamma,
                                                 const float* __restrict__ beta,
                                                 ushort_t* __restrict__ H, int n) {
    int i = blockIdx.x * 256 + threadIdx.x;  // one thread = 2 channels
    if (i >= n * 64) return;
    int nd = i >> 6;
    int c = (i & 63) << 1;
    float inv_n = 1.f / (float)n;
    float mu0 = stats[c] * inv_n, mu1 = stats[c + 1] * inv_n;
    float v0 = stats[128 + c] * inv_n - mu0 * mu0;
    float v1 = stats[128 + c + 1] * inv_n - mu1 * mu1;
    float s0 = rsqrtf(v0 + WS_EPS) * gamma[c];
    float s1 = rsqrtf(v1 + WS_EPS) * gamma[c + 1];
    uint_t pv = *(const uint_t*)&P[(size_t)nd * 128 + c];
    uint_t xv = *(const uint_t*)&Xb[(size_t)nd * 128 + c];
    float p0 = __uint_as_float(pv << 16);
    float p1 = __uint_as_float(pv & 0xffff0000u);
    float x0 = __uint_as_float(xv << 16);
    float x1 = __uint_as_float(xv & 0xffff0000u);
    float h0 = fmaxf((p0 - mu0) * s0 + beta[c], 0.f) + x0;
    float h1 = fmaxf((p1 - mu1) * s1 + beta[c + 1], 0.f) + x1;
    uint_t pk = (uint_t)f2bf(h0) | ((uint_t)f2bf(h1) << 16);
    *(uint_t*)&H[(size_t)nd * 128 + c] = pk;
}

// ---------------------------------------------------------------------------
extern "C" void kernel_launch(void* const* d_in, const int* in_sizes, int n_in,
                              void* d_out, int out_size, void* d_ws, size_t ws_size,
                              hipStream_t stream) {
    const float* x     = (const float*)d_in[0];
    const int*   ei    = (const int*)d_in[1];
    const float* Wl0   = (const float*)d_in[2];
    const float* Wr0   = (const float*)d_in[3];
    const float* b0    = (const float*)d_in[4];
    const float* Wl1   = (const float*)d_in[5];
    const float* Wr1   = (const float*)d_in[6];
    const float* b1    = (const float*)d_in[7];
    const float* Wl2   = (const float*)d_in[8];
    const float* Wr2   = (const float*)d_in[9];
    const float* b2    = (const float*)d_in[10];
    const float* gamma = (const float*)d_in[11];
    const float* beta  = (const float*)d_in[12];

    const int n = in_sizes[0] / 128;
    const int E = in_sizes[1] / 2;
    const int nb_scan = (n + SCHUNK - 1) / SCHUNK;

    char* w = (char*)d_ws;
    auto alloc = [&](size_t bytes) -> void* {
        void* p = (void*)w;
        w += (bytes + 255) & ~(size_t)255;
        return p;
    };
    int*      deg   = (int*)alloc((size_t)n * 4);
    int*      cur   = (int*)alloc((size_t)n * 4);
    float*    stats = (float*)alloc(256 * 4);
    size_t    zbytes = (size_t)((char*)w - (char*)deg);
    int*      off   = (int*)alloc(((size_t)n + 1) * 4);
    int*      csr   = (int*)alloc((size_t)E * 4);
    int*      bsum  = (int*)alloc(256 * 4);
    int*      boff  = (int*)alloc(256 * 4);
    ushort_t* wts   = (ushort_t*)alloc((size_t)81920 * 2);
    ushort_t* xb    = (ushort_t*)alloc((size_t)n * 128 * 2);
    uchar_t*  x8    = (uchar_t*)alloc((size_t)n * 128);
    ushort_t* H     = (ushort_t*)alloc((size_t)n * 128 * 2);
    uchar_t*  H8    = (uchar_t*)alloc((size_t)n * 128);
    ushort_t* Pb    = (ushort_t*)alloc((size_t)n * 128 * 2);
    ushort_t* M     = (ushort_t*)alloc((size_t)n * 128 * 2);
    ushort_t* A64   = (ushort_t*)alloc((size_t)n * 64 * 2);
    ushort_t* Tb    = (ushort_t*)alloc((size_t)n * 64 * 2);

    ushort_t* WtL0 = wts;
    ushort_t* WtR0 = wts + 16384;
    ushort_t* WtL1 = wts + 32768;
    ushort_t* WtR1 = wts + 49152;
    ushort_t* WtL2 = wts + 65536;
    ushort_t* WtR2 = wts + 73728;

    hipMemsetAsync(deg, 0, zbytes, stream);

    const int eb = (E + 255) / 256;
    const int nb_cvt = (n * 64 + 255) / 256;
    k_deg_prep<<<eb + nb_cvt + 320, 256, 0, stream>>>(ei, deg, E, eb, x, xb, x8,
                                                      n * 64, nb_cvt,
                                                      Wl0, Wr0, Wl1, Wr1, Wl2, Wr2, wts);
    k_scan_part<<<nb_scan, 256, 0, stream>>>(deg, bsum, n);
    k_scan_bsum<<<1, 64, 0, stream>>>(bsum, boff, off + n, nb_scan);
    k_scan_apply<<<nb_scan, 256, 0, stream>>>(deg, boff, off, n);
    k_scatter<<<(E + 255) / 256, 256, 0, stream>>>(ei, off, cur, csr, E);

    const int strips = (n + 15) / 16;
    const int gb_d = (strips + 1) / 2;   // 2 strips/block (2 waves each)
    const int gb_c = (strips + 3) / 4;   // 4 strips/block (1 wave each)
    const int smb = (n + 31) / 32;

    // layer 0: M = segmean(x8); H,H8 = relu(xb@Wr0 + M@Wl0 + b0)
    k_segmean8<<<smb, 256, 0, stream>>>(x8, off, csr, M, n);
    k_dgemm<2><<<gb_d, 256, 0, stream>>>(xb, WtR0, M, WtL0, b0, H, H8, nullptr, n);

    // layer 1: M = segmean(H8); Pb = H@Wr1 + M@Wl1 + b1 (+BN stats);
    //          H = bf16(relu(BN(Pb)) + xb)
    k_segmean8<<<smb, 256, 0, stream>>>(H8, off, csr, M, n);
    k_dgemm<1><<<gb_d, 256, 0, stream>>>(H, WtR1, M, WtL1, b1, Pb, nullptr, stats, n);
    k_bnapply<<<(n * 64 + 255) / 256, 256, 0, stream>>>(Pb, xb, stats, gamma, beta, H, n);

    // layer 2: {A64 = H@Wl2, Tb = H@Wr2 + b2}; out = lsm(segmean(A64) + Tb)
    k_cgemm<<<gb_c, 256, 0, stream>>>(H, WtL2, WtR2, b2, A64, Tb, n);
    k_segmean_lsm<<<smb, 256, 0, stream>>>(A64, off, csr, Tb, (float*)d_out, n);
}

// Round 15
// 251.017 us; speedup vs baseline: 1.2243x; 1.2243x over previous
//
#include <hip/hip_runtime.h>
#include <hip/hip_bf16.h>

// ---------------------------------------------------------------------------
// GraphSAGE 3-layer forward. bf16 MFMA GEMMs (f32 accum).
// R15 GEMM structure: B staged in LDS in FRAGMENT-MAJOR layout — each
// (mat,fn,ks) fragment is a contiguous 64-lane x 16B record, so every
// ds_read_b128 is lane*16+imm (canonical conflict-free; R13's [col][k]
// layout was an 8-way conflict, SQ_LDS_BANK_CONFLICT saturated). One-shot
// blocks (no persistence), one barrier, W-loads -> A-loads -> ds_writes ->
// barrier -> MFMA. hipcc won't keep B in VGPRs (R6/R7/R14: rematerializes),
// so LDS is the only conflict-free home for B.
//   layer0: H,H8 = relu(x@Wr0 + segmean8(x8)@Wl0 + b0)
//   layer1: Pb = H@Wr1 + segmean8(H8)@Wl1 + b1; stats = bnstats(Pb);
//           H = bf16(relu(BN(Pb)) + xb)
//   layer2: {A64 = H@Wl2, Tb = H@Wr2 + b2}; out = log_softmax(segmean(A64)+Tb)
// ---------------------------------------------------------------------------

#define WS_EPS 1e-5f

typedef unsigned short ushort_t;
typedef unsigned int uint_t;
typedef unsigned char uchar_t;
typedef ushort_t ushort8 __attribute__((ext_vector_type(8)));
typedef short short8 __attribute__((ext_vector_type(8)));
typedef float f32x4 __attribute__((ext_vector_type(4)));
typedef _Float16 half2v __attribute__((ext_vector_type(2)));

__device__ __forceinline__ float bf2f(ushort_t u) {
    return __uint_as_float(((uint_t)u) << 16);
}
__device__ __forceinline__ ushort_t f2bf(float f) {
    uint_t u = __float_as_uint(f);
    u = (u + 0x7fffu + ((u >> 16) & 1u)) >> 16;  // RNE
    return (ushort_t)u;
}
// f32 -> OCP e4m3fn with flush-to-zero of subnormals (decode = pure bit ops)
__device__ __forceinline__ uchar_t f2e4m3(float f) {
    _Float16 hf = (_Float16)f;  // RNE
    uint_t h = (uint_t)__builtin_bit_cast(unsigned short, hf);
    uint_t s = (h >> 8) & 0x80u;
    uint_t r = h & 0x7fffu;
    if (r < 0x2400u) return (uchar_t)0;   // |v| < 2^-6 -> 0
    if (r > 0x5F40u) r = 0x5F00u;         // clamp to 448
    uint_t u = r - 0x2000u;
    uint_t m = (u + 0x3fu + ((u >> 7) & 1u)) >> 7;  // RNE to 3-bit mantissa
    return (uchar_t)(s | m);
}

// ---- CSR build -------------------------------------------------------------
constexpr int SCHUNK = 4096;

__global__ __launch_bounds__(256) void k_scan_part(const int* __restrict__ deg,
                                                   int* __restrict__ bsum, int n) {
    int t = threadIdx.x;
    int base = blockIdx.x * SCHUNK + t * 16;
    int s = 0;
#pragma unroll
    for (int j = 0; j < 16; ++j) {
        int i = base + j;
        if (i < n) s += deg[i];
    }
#pragma unroll
    for (int d = 1; d < 64; d <<= 1) s += __shfl_xor(s, d);
    __shared__ int wt[4];
    if ((t & 63) == 0) wt[t >> 6] = s;
    __syncthreads();
    if (t == 0) bsum[blockIdx.x] = wt[0] + wt[1] + wt[2] + wt[3];
}

__global__ __launch_bounds__(64) void k_scan_bsum(const int* __restrict__ bsum,
                                                  int* __restrict__ boff,
                                                  int* __restrict__ off_n, int nb) {
    int lane = threadIdx.x;
    int carry = 0;
    for (int base = 0; base < nb; base += 64) {
        int t = base + lane;
        int v = (t < nb) ? bsum[t] : 0;
        int x = v;
#pragma unroll
        for (int d = 1; d < 64; d <<= 1) {
            int y = __shfl_up(x, d);
            if (lane >= d) x += y;
        }
        if (t < nb) boff[t] = carry + x - v;
        carry += __shfl(x, 63);
    }
    if (lane == 0) *off_n = carry;
}

__global__ __launch_bounds__(256) void k_scan_apply(const int* __restrict__ deg,
                                                    const int* __restrict__ boff,
                                                    int* __restrict__ off, int n) {
    int t = threadIdx.x;
    int lane = t & 63, wid = t >> 6;
    int base = blockIdx.x * SCHUNK + t * 16;
    int v[16];
    int s = 0;
#pragma unroll
    for (int j = 0; j < 16; ++j) {
        int i = base + j;
        v[j] = (i < n) ? deg[i] : 0;
        s += v[j];
    }
    int x = s;
#pragma unroll
    for (int d = 1; d < 64; d <<= 1) {
        int y = __shfl_up(x, d);
        if (lane >= d) x += y;
    }
    __shared__ int wtot[4];
    if (lane == 63) wtot[wid] = x;
    __syncthreads();
    int woff = 0;
    for (int wj = 0; wj < wid; ++wj) woff += wtot[wj];
    int run = boff[blockIdx.x] + woff + x - s;
#pragma unroll
    for (int j = 0; j < 16; ++j) {
        int i = base + j;
        if (i < n) off[i] = run;
        run += v[j];
    }
}

__global__ __launch_bounds__(256) void k_scatter(const int* __restrict__ ei,
                                                 const int* __restrict__ off,
                                                 int* __restrict__ cur,
                                                 int* __restrict__ csr, int E) {
    int e = blockIdx.x * 256 + threadIdx.x;
    if (e < E) {
        int d = ei[E + e];
        int s = ei[e];
        int p = atomicAdd(&cur[d], 1);
        csr[off[d] + p] = s;
    }
}

// ---- fused: degree count | x->bf16+fp8 | weights->bf16 transposed ----------
__global__ __launch_bounds__(256) void k_deg_prep(const int* __restrict__ ei,
                                                  int* __restrict__ deg, int E, int eb,
                                                  const float* __restrict__ x,
                                                  ushort_t* __restrict__ xb,
                                                  uchar_t* __restrict__ x8,
                                                  int total2, int nb_cvt,
                                                  const float* __restrict__ Wl0,
                                                  const float* __restrict__ Wr0,
                                                  const float* __restrict__ Wl1,
                                                  const float* __restrict__ Wr1,
                                                  const float* __restrict__ Wl2,
                                                  const float* __restrict__ Wr2,
                                                  ushort_t* __restrict__ wts) {
    int b = blockIdx.x;
    if (b < eb) {
        int e = b * 256 + threadIdx.x;
        if (e < E) atomicAdd(&deg[ei[E + e]], 1);
        return;
    }
    b -= eb;
    if (b < nb_cvt) {
        int i = b * 256 + threadIdx.x;
        if (i >= total2) return;
        float2 v = *(const float2*)&x[(size_t)i * 2];
        uint_t p = (uint_t)f2bf(v.x) | ((uint_t)f2bf(v.y) << 16);
        *(uint_t*)&xb[(size_t)i * 2] = p;
        ushort_t q = (ushort_t)((uint_t)f2e4m3(v.x) | ((uint_t)f2e4m3(v.y) << 8));
        *(ushort_t*)&x8[(size_t)i * 2] = q;
        return;
    }
    int id = (b - nb_cvt) * 256 + threadIdx.x;
    if (id >= 81920) return;
    const float* W;
    int rel, nout, base;
    if (id < 65536) {
        int m = id >> 14;
        rel = id & 16383;
        nout = 128;
        base = m << 14;
        W = (m == 0) ? Wl0 : (m == 1) ? Wr0 : (m == 2) ? Wl1 : Wr1;
    } else {
        int m = (id - 65536) >> 13;
        rel = (id - 65536) & 8191;
        nout = 64;
        base = 65536 + (m << 13);
        W = (m == 0) ? Wl2 : Wr2;
    }
    int c = rel >> 7;
    int k = rel & 127;
    wts[base + rel] = f2bf(W[(size_t)k * nout + c]);
}

// ---- dual GEMM: fragment-major LDS B, one col-half x 4 strips per block ----
// out[n][128] = X1@W1 + X2@W2 + bias. LDS slot (mat,fn,ks,lane) -> 16B at
// ((mat*16+fn*4+ks)*64+lane)*16: ds_read_b128 = lane*16 + imm, conflict-free.
// EPI: 2 -> relu, bf16 out + fp8 out8 (layer 0); 1 -> bf16 out (layer 1).
template <int EPI>
__global__ __launch_bounds__(256, 4) void k_dgemm(const ushort_t* __restrict__ X1,
                                                  const ushort_t* __restrict__ W1,
                                                  const ushort_t* __restrict__ X2,
                                                  const ushort_t* __restrict__ W2,
                                                  const float* __restrict__ bias,
                                                  ushort_t* __restrict__ outp,
                                                  uchar_t* __restrict__ out8, int n) {
    constexpr int K = 128, NOUT = 128;
    __shared__ ushort_t Bs[2048 * 8];  // 32 KB, fragment-major

    const int t = threadIdx.x;
    const int lane = t & 63;
    const int r16 = lane & 15, kb = lane >> 4;
    const int half = blockIdx.x & 1;
    const int colbase = half * 64;
    const int strip = (blockIdx.x >> 1) * 4 + (t >> 6);
    const int strips = (n + 15) >> 4;

    // 1) issue W staging loads (8 ushort8)
    ushort8 wreg[8];
#pragma unroll
    for (int u = 0; u < 8; ++u) {
        int slot = u * 256 + t;
        int mat = slot >> 10;
        int rem = slot & 1023;
        int fnks = rem >> 6;
        int l = rem & 63;
        int fn = fnks >> 2, ks = fnks & 3;
        const ushort_t* Wm = mat ? W2 : W1;
        wreg[u] = *(const ushort8*)&Wm[(size_t)(colbase + fn * 16 + (l & 15)) * K +
                                       ks * 32 + (l >> 4) * 8];
    }
    // 2) issue A loads (8 ushort8) — latency hides under staging + barrier
    const int arow = strip * 16 + r16;
    const bool rok = (arow < n);
    const size_t xo = (size_t)arow * K + kb * 8;
    short8 a1[4], a2[4];
#pragma unroll
    for (int ks = 0; ks < 4; ++ks)
        a1[ks] = rok ? *(const short8*)&X1[xo + ks * 32] : (short8)0;
#pragma unroll
    for (int ks = 0; ks < 4; ++ks)
        a2[ks] = rok ? *(const short8*)&X2[xo + ks * 32] : (short8)0;
    // 3) land staging
#pragma unroll
    for (int u = 0; u < 8; ++u) {
        int slot = u * 256 + t;
        *(ushort8*)&Bs[(size_t)slot * 8] = wreg[u];
    }
    __syncthreads();

    f32x4 acc[4] = {(f32x4)0.f, (f32x4)0.f, (f32x4)0.f, (f32x4)0.f};
#pragma unroll
    for (int ks = 0; ks < 4; ++ks)
#pragma unroll
        for (int fn = 0; fn < 4; ++fn) {
            short8 b = *(const short8*)&Bs[((fn * 4 + ks) * 64 + lane) * 8];
            acc[fn] = __builtin_amdgcn_mfma_f32_16x16x32_bf16(a1[ks], b, acc[fn], 0, 0, 0);
        }
#pragma unroll
    for (int ks = 0; ks < 4; ++ks)
#pragma unroll
        for (int fn = 0; fn < 4; ++fn) {
            short8 b = *(const short8*)&Bs[((16 + fn * 4 + ks) * 64 + lane) * 8];
            acc[fn] = __builtin_amdgcn_mfma_f32_16x16x32_bf16(a2[ks], b, acc[fn], 0, 0, 0);
        }

    float bcol[4];
#pragma unroll
    for (int fn = 0; fn < 4; ++fn) bcol[fn] = bias[colbase + fn * 16 + r16];

    const int rb = strip * 16 + kb * 4;
#pragma unroll
    for (int r = 0; r < 4; ++r) {
        int row = rb + r;
        if (row >= n) continue;
#pragma unroll
        for (int fn = 0; fn < 4; ++fn) {
            int col = colbase + fn * 16 + r16;
            float v = acc[fn][r] + bcol[fn];
            if constexpr (EPI == 2) {
                v = fmaxf(v, 0.f);
                outp[(size_t)row * NOUT + col] = f2bf(v);
                out8[(size_t)row * NOUT + col] = f2e4m3(v);
            } else {
                outp[(size_t)row * NOUT + col] = f2bf(v);
            }
        }
    }
}

// ---- layer-2 GEMM: fragment-major LDS (both mats), 4 strips per block ------
// A64 = H@Wl2 (bf16), Tb = H@Wr2 + b2 (bf16).
__global__ __launch_bounds__(256, 4) void k_cgemm(const ushort_t* __restrict__ H,
                                                  const ushort_t* __restrict__ WL,
                                                  const ushort_t* __restrict__ WR,
                                                  const float* __restrict__ b2,
                                                  ushort_t* __restrict__ A64,
                                                  ushort_t* __restrict__ Tb, int n) {
    constexpr int K = 128;
    __shared__ ushort_t Bs[2048 * 8];  // 32 KB

    const int t = threadIdx.x;
    const int lane = t & 63;
    const int r16 = lane & 15, kb = lane >> 4;
    const int strip = blockIdx.x * 4 + (t >> 6);
    const int strips = (n + 15) >> 4;
    (void)strips;

    ushort8 wreg[8];
#pragma unroll
    for (int u = 0; u < 8; ++u) {
        int slot = u * 256 + t;
        int mat = slot >> 10;
        int rem = slot & 1023;
        int fnks = rem >> 6;
        int l = rem & 63;
        int fn = fnks >> 2, ks = fnks & 3;
        const ushort_t* Wm = mat ? WR : WL;
        wreg[u] = *(const ushort8*)&Wm[(size_t)(fn * 16 + (l & 15)) * K +
                                       ks * 32 + (l >> 4) * 8];
    }
    const int arow = strip * 16 + r16;
    const bool rok = (arow < n);
    const size_t xo = (size_t)arow * K + kb * 8;
    short8 a[4];
#pragma unroll
    for (int ks = 0; ks < 4; ++ks)
        a[ks] = rok ? *(const short8*)&H[xo + ks * 32] : (short8)0;
#pragma unroll
    for (int u = 0; u < 8; ++u) {
        int slot = u * 256 + t;
        *(ushort8*)&Bs[(size_t)slot * 8] = wreg[u];
    }
    __syncthreads();

    f32x4 aL[4] = {(f32x4)0.f, (f32x4)0.f, (f32x4)0.f, (f32x4)0.f};
    f32x4 aR[4] = {(f32x4)0.f, (f32x4)0.f, (f32x4)0.f, (f32x4)0.f};
#pragma unroll
    for (int ks = 0; ks < 4; ++ks)
#pragma unroll
        for (int fn = 0; fn < 4; ++fn) {
            short8 bl = *(const short8*)&Bs[((fn * 4 + ks) * 64 + lane) * 8];
            short8 br = *(const short8*)&Bs[((16 + fn * 4 + ks) * 64 + lane) * 8];
            aL[fn] = __builtin_amdgcn_mfma_f32_16x16x32_bf16(a[ks], bl, aL[fn], 0, 0, 0);
            aR[fn] = __builtin_amdgcn_mfma_f32_16x16x32_bf16(a[ks], br, aR[fn], 0, 0, 0);
        }

    float bcol[4];
#pragma unroll
    for (int fn = 0; fn < 4; ++fn) bcol[fn] = b2[fn * 16 + r16];

    const int rb = strip * 16 + kb * 4;
#pragma unroll
    for (int r = 0; r < 4; ++r) {
        int row = rb + r;
        if (row >= n) continue;
#pragma unroll
        for (int fn = 0; fn < 4; ++fn) {
            int col = fn * 16 + r16;
            A64[(size_t)row * 64 + col] = f2bf(aL[fn][r]);
            Tb[(size_t)row * 64 + col] = f2bf(aR[fn][r] + bcol[fn]);
        }
    }
}

// ---- BN stats over Pb (bf16): per-channel sum & sumsq ----------------------
__global__ __launch_bounds__(256) void k_bnstats(const ushort_t* __restrict__ P,
                                                 float* __restrict__ stats, int n) {
    int t = threadIdx.x;
    int c2 = t & 63;   // column pair
    int h = t >> 6;    // 0..3
    int r0 = blockIdx.x * 64;
    int rend = min(r0 + 64, n);
    float s0 = 0.f, s1 = 0.f, q0 = 0.f, q1 = 0.f;
    for (int r = r0 + h; r < rend; r += 4) {
        uint_t pv = *(const uint_t*)&P[(size_t)r * 128 + c2 * 2];
        float p0 = __uint_as_float(pv << 16);
        float p1 = __uint_as_float(pv & 0xffff0000u);
        s0 += p0;
        q0 += p0 * p0;
        s1 += p1;
        q1 += p1 * p1;
    }
    __shared__ float sh[4][64][4];
    sh[h][c2][0] = s0;
    sh[h][c2][1] = s1;
    sh[h][c2][2] = q0;
    sh[h][c2][3] = q1;
    __syncthreads();
    if (h == 0) {
        float S0 = 0.f, S1 = 0.f, Q0 = 0.f, Q1 = 0.f;
#pragma unroll
        for (int j = 0; j < 4; ++j) {
            S0 += sh[j][c2][0];
            S1 += sh[j][c2][1];
            Q0 += sh[j][c2][2];
            Q1 += sh[j][c2][3];
        }
        atomicAdd(&stats[c2 * 2], S0);
        atomicAdd(&stats[c2 * 2 + 1], S1);
        atomicAdd(&stats[128 + c2 * 2], Q0);
        atomicAdd(&stats[128 + c2 * 2 + 1], Q1);
    }
}

// ---- segment mean over CSR, fp8 in -> bf16 out. 8 lanes/node, 16 ch/lane ---
__global__ __launch_bounds__(256) void k_segmean8(const uchar_t* __restrict__ U8,
                                                  const int* __restrict__ off,
                                                  const int* __restrict__ srcs,
                                                  ushort_t* __restrict__ out, int n) {
    int node = blockIdx.x * 32 + (threadIdx.x >> 3);
    int sub = threadIdx.x & 7;
    if (node >= n) return;
    int beg = off[node], end = off[node + 1];
    half2v aE0 = (half2v)0, aE1 = (half2v)0, aE2 = (half2v)0, aE3 = (half2v)0;
    half2v aO0 = (half2v)0, aO1 = (half2v)0, aO2 = (half2v)0, aO3 = (half2v)0;

#define DEC(dw, AE, AO)                                                           \
    {                                                                             \
        uint_t xe = (dw)&0x00ff00ffu;                                             \
        uint_t xo = ((dw) >> 8) & 0x00ff00ffu;                                    \
        uint_t he = ((xe & 0x00800080u) << 8) |                                   \
                    (((xe & 0x007f007fu) << 7) + 0x20002000u);                    \
        uint_t ho = ((xo & 0x00800080u) << 8) |                                   \
                    (((xo & 0x007f007fu) << 7) + 0x20002000u);                    \
        AE += __builtin_bit_cast(half2v, he);                                     \
        AO += __builtin_bit_cast(half2v, ho);                                     \
    }

    auto addrow = [&](int sidx) {
        uint4 v = *(const uint4*)&U8[(size_t)sidx * 128 + sub * 16];
        DEC(v.x, aE0, aO0)
        DEC(v.y, aE1, aO1)
        DEC(v.z, aE2, aO2)
        DEC(v.w, aE3, aO3)
    };
#undef DEC

    int i = beg;
    for (; i + 8 <= end; i += 8) {
        int sv[8];
#pragma unroll
        for (int u = 0; u < 8; ++u) sv[u] = srcs[i + u];
#pragma unroll
        for (int u = 0; u < 8; ++u) addrow(sv[u]);
    }
    for (; i < end; ++i) addrow(srcs[i]);

    int d = end - beg;
    float inv = 1.f / (float)(d > 1 ? d : 1);
    ushort8 o0, o1;
#define PACK(AE, AO, O, IDX)                     \
    O[IDX] = f2bf((float)AE[0] * inv);           \
    O[IDX + 1] = f2bf((float)AO[0] * inv);       \
    O[IDX + 2] = f2bf((float)AE[1] * inv);       \
    O[IDX + 3] = f2bf((float)AO[1] * inv);
    PACK(aE0, aO0, o0, 0)
    PACK(aE1, aO1, o0, 4)
    PACK(aE2, aO2, o1, 0)
    PACK(aE3, aO3, o1, 4)
#undef PACK
    *(ushort8*)&out[(size_t)node * 128 + sub * 16] = o0;
    *(ushort8*)&out[(size_t)node * 128 + sub * 16 + 8] = o1;
}

// ---- fused 64-d segmean + log_softmax: out = lsm(segmean(A64) + Tb) --------
__global__ __launch_bounds__(256) void k_segmean_lsm(const ushort_t* __restrict__ A64,
                                                     const int* __restrict__ off,
                                                     const int* __restrict__ srcs,
                                                     const ushort_t* __restrict__ Tb,
                                                     float* __restrict__ out, int n) {
    int node = blockIdx.x * 32 + (threadIdx.x >> 3);
    int sub = threadIdx.x & 7;
    if (node >= n) return;
    int beg = off[node], end = off[node + 1];
    float a[8];
#pragma unroll
    for (int j = 0; j < 8; ++j) a[j] = 0.f;
    int i = beg;
    for (; i + 8 <= end; i += 8) {
        int sv[8];
#pragma unroll
        for (int u = 0; u < 8; ++u) sv[u] = srcs[i + u];
#pragma unroll
        for (int u = 0; u < 8; ++u) {
            ushort8 v = *(const ushort8*)&A64[(size_t)sv[u] * 64 + sub * 8];
#pragma unroll
            for (int j = 0; j < 8; ++j) a[j] += bf2f((ushort_t)v[j]);
        }
    }
    for (; i < end; ++i) {
        ushort8 v = *(const ushort8*)&A64[(size_t)srcs[i] * 64 + sub * 8];
#pragma unroll
        for (int j = 0; j < 8; ++j) a[j] += bf2f((ushort_t)v[j]);
    }
    int d = end - beg;
    float inv = 1.f / (float)(d > 1 ? d : 1);
    ushort8 tv = *(const ushort8*)&Tb[(size_t)node * 64 + sub * 8];
    float vv[8];
#pragma unroll
    for (int j = 0; j < 8; ++j) vv[j] = a[j] * inv + bf2f((ushort_t)tv[j]);
    float m = vv[0];
#pragma unroll
    for (int j = 1; j < 8; ++j) m = fmaxf(m, vv[j]);
#pragma unroll
    for (int dd = 1; dd < 8; dd <<= 1) m = fmaxf(m, __shfl_xor(m, dd));
    float e = 0.f;
#pragma unroll
    for (int j = 0; j < 8; ++j) e += expf(vv[j] - m);
#pragma unroll
    for (int dd = 1; dd < 8; dd <<= 1) e += __shfl_xor(e, dd);
    float lg = m + logf(e);
    f32x4 o0, o1;
#pragma unroll
    for (int j = 0; j < 4; ++j) {
        o0[j] = vv[j] - lg;
        o1[j] = vv[4 + j] - lg;
    }
    *(f32x4*)&out[(size_t)node * 64 + sub * 8] = o0;
    *(f32x4*)&out[(size_t)node * 64 + sub * 8 + 4] = o1;
}

// ---- BN apply + relu + residual (xb bf16), Pb bf16 -> H bf16 ---------------
__global__ __launch_bounds__(256) void k_bnapply(const ushort_t* __restrict__ P,
                                                 const ushort_t* __restrict__ Xb,
                                                 const float* __restrict__ stats,
                                                 const float* __restrict__ gamma,
                                                 const float* __restrict__ beta,
                                                 ushort_t* __restrict__ H, int n) {
    int i = blockIdx.x * 256 + threadIdx.x;  // one thread = 2 channels
    if (i >= n * 64) return;
    int nd = i >> 6;
    int c = (i & 63) << 1;
    float inv_n = 1.f / (float)n;
    float mu0 = stats[c] * inv_n, mu1 = stats[c + 1] * inv_n;
    float v0 = stats[128 + c] * inv_n - mu0 * mu0;
    float v1 = stats[128 + c + 1] * inv_n - mu1 * mu1;
    float s0 = rsqrtf(v0 + WS_EPS) * gamma[c];
    float s1 = rsqrtf(v1 + WS_EPS) * gamma[c + 1];
    uint_t pv = *(const uint_t*)&P[(size_t)nd * 128 + c];
    uint_t xv = *(const uint_t*)&Xb[(size_t)nd * 128 + c];
    float p0 = __uint_as_float(pv << 16);
    float p1 = __uint_as_float(pv & 0xffff0000u);
    float x0 = __uint_as_float(xv << 16);
    float x1 = __uint_as_float(xv & 0xffff0000u);
    float h0 = fmaxf((p0 - mu0) * s0 + beta[c], 0.f) + x0;
    float h1 = fmaxf((p1 - mu1) * s1 + beta[c + 1], 0.f) + x1;
    uint_t pk = (uint_t)f2bf(h0) | ((uint_t)f2bf(h1) << 16);
    *(uint_t*)&H[(size_t)nd * 128 + c] = pk;
}

// ---------------------------------------------------------------------------
extern "C" void kernel_launch(void* const* d_in, const int* in_sizes, int n_in,
                              void* d_out, int out_size, void* d_ws, size_t ws_size,
                              hipStream_t stream) {
    const float* x     = (const float*)d_in[0];
    const int*   ei    = (const int*)d_in[1];
    const float* Wl0   = (const float*)d_in[2];
    const float* Wr0   = (const float*)d_in[3];
    const float* b0    = (const float*)d_in[4];
    const float* Wl1   = (const float*)d_in[5];
    const float* Wr1   = (const float*)d_in[6];
    const float* b1    = (const float*)d_in[7];
    const float* Wl2   = (const float*)d_in[8];
    const float* Wr2   = (const float*)d_in[9];
    const float* b2    = (const float*)d_in[10];
    const float* gamma = (const float*)d_in[11];
    const float* beta  = (const float*)d_in[12];

    const int n = in_sizes[0] / 128;
    const int E = in_sizes[1] / 2;
    const int nb_scan = (n + SCHUNK - 1) / SCHUNK;

    char* w = (char*)d_ws;
    auto alloc = [&](size_t bytes) -> void* {
        void* p = (void*)w;
        w += (bytes + 255) & ~(size_t)255;
        return p;
    };
    int*      deg   = (int*)alloc((size_t)n * 4);
    int*      cur   = (int*)alloc((size_t)n * 4);
    float*    stats = (float*)alloc(256 * 4);
    size_t    zbytes = (size_t)((char*)w - (char*)deg);
    int*      off   = (int*)alloc(((size_t)n + 1) * 4);
    int*      csr   = (int*)alloc((size_t)E * 4);
    int*      bsum  = (int*)alloc(256 * 4);
    int*      boff  = (int*)alloc(256 * 4);
    ushort_t* wts   = (ushort_t*)alloc((size_t)81920 * 2);
    ushort_t* xb    = (ushort_t*)alloc((size_t)n * 128 * 2);
    uchar_t*  x8    = (uchar_t*)alloc((size_t)n * 128);
    ushort_t* H     = (ushort_t*)alloc((size_t)n * 128 * 2);
    uchar_t*  H8    = (uchar_t*)alloc((size_t)n * 128);
    ushort_t* Pb    = (ushort_t*)alloc((size_t)n * 128 * 2);
    ushort_t* M     = (ushort_t*)alloc((size_t)n * 128 * 2);
    ushort_t* A64   = (ushort_t*)alloc((size_t)n * 64 * 2);
    ushort_t* Tb    = (ushort_t*)alloc((size_t)n * 64 * 2);

    ushort_t* WtL0 = wts;
    ushort_t* WtR0 = wts + 16384;
    ushort_t* WtL1 = wts + 32768;
    ushort_t* WtR1 = wts + 49152;
    ushort_t* WtL2 = wts + 65536;
    ushort_t* WtR2 = wts + 73728;

    hipMemsetAsync(deg, 0, zbytes, stream);

    const int eb = (E + 255) / 256;
    const int nb_cvt = (n * 64 + 255) / 256;
    k_deg_prep<<<eb + nb_cvt + 320, 256, 0, stream>>>(ei, deg, E, eb, x, xb, x8,
                                                      n * 64, nb_cvt,
                                                      Wl0, Wr0, Wl1, Wr1, Wl2, Wr2, wts);
    k_scan_part<<<nb_scan, 256, 0, stream>>>(deg, bsum, n);
    k_scan_bsum<<<1, 64, 0, stream>>>(bsum, boff, off + n, nb_scan);
    k_scan_apply<<<nb_scan, 256, 0, stream>>>(deg, boff, off, n);
    k_scatter<<<(E + 255) / 256, 256, 0, stream>>>(ei, off, cur, csr, E);

    const int strips = (n + 15) / 16;
    const int gb_d = 2 * ((strips + 3) / 4);  // halves x strip-quads
    const int gb_c = (strips + 3) / 4;
    const int smb = (n + 31) / 32;

    // layer 0: M = segmean(x8); H,H8 = relu(xb@Wr0 + M@Wl0 + b0)
    k_segmean8<<<smb, 256, 0, stream>>>(x8, off, csr, M, n);
    k_dgemm<2><<<gb_d, 256, 0, stream>>>(xb, WtR0, M, WtL0, b0, H, H8, n);

    // layer 1: M = segmean(H8); Pb = H@Wr1 + M@Wl1 + b1; stats; BN apply
    k_segmean8<<<smb, 256, 0, stream>>>(H8, off, csr, M, n);
    k_dgemm<1><<<gb_d, 256, 0, stream>>>(H, WtR1, M, WtL1, b1, Pb, nullptr, n);
    k_bnstats<<<(n + 63) / 64, 256, 0, stream>>>(Pb, stats, n);
    k_bnapply<<<(n * 64 + 255) / 256, 256, 0, stream>>>(Pb, xb, stats, gamma, beta, H, n);

    // layer 2: {A64 = H@Wl2, Tb = H@Wr2 + b2}; out = lsm(segmean(A64) + Tb)
    k_cgemm<<<gb_c, 256, 0, stream>>>(H, WtL2, WtR2, b2, A64, Tb, n);
    k_segmean_lsm<<<smb, 256, 0, stream>>>(A64, off, csr, Tb, (float*)d_out, n);
}

// Round 16
// 224.946 us; speedup vs baseline: 1.3662x; 1.1159x over previous
//
#include <hip/hip_runtime.h>
#include <hip/hip_bf16.h>

// ---------------------------------------------------------------------------
// GraphSAGE 3-layer forward. bf16 MFMA GEMMs (f32 accum).
// R16: consolidation.
//  - BN stats fused back into dgemm<1> epilogue (R13-proven: ~zero cost;
//    R15's separate k_bnstats ran at VGPR=8 -> serialized loads, 43.6us).
//  - dgemm strip-pairing: 2 strips/wave, each B ds_read feeds 2 MFMAs,
//    half the blocks -> half the W-staging traffic.
//  - GEMM LDS is fragment-major (R15): ds_read_b128 = lane*16+imm,
//    conflict-free (R13's [col][k] was 8-way conflicted).
//   layer0: H,H8 = relu(x@Wr0 + segmean8(x8)@Wl0 + b0)
//   layer1: Pb = H@Wr1 + segmean8(H8)@Wl1 + b1 (+f32 BN stats in epilogue);
//           H = bf16(relu(BN(Pb)) + xb)
//   layer2: {A64 = H@Wl2, Tb = H@Wr2 + b2}; out = log_softmax(segmean(A64)+Tb)
// ---------------------------------------------------------------------------

#define WS_EPS 1e-5f

typedef unsigned short ushort_t;
typedef unsigned int uint_t;
typedef unsigned char uchar_t;
typedef ushort_t ushort8 __attribute__((ext_vector_type(8)));
typedef short short8 __attribute__((ext_vector_type(8)));
typedef float f32x4 __attribute__((ext_vector_type(4)));
typedef _Float16 half2v __attribute__((ext_vector_type(2)));

__device__ __forceinline__ float bf2f(ushort_t u) {
    return __uint_as_float(((uint_t)u) << 16);
}
__device__ __forceinline__ ushort_t f2bf(float f) {
    uint_t u = __float_as_uint(f);
    u = (u + 0x7fffu + ((u >> 16) & 1u)) >> 16;  // RNE
    return (ushort_t)u;
}
// f32 -> OCP e4m3fn with flush-to-zero of subnormals (decode = pure bit ops)
__device__ __forceinline__ uchar_t f2e4m3(float f) {
    _Float16 hf = (_Float16)f;  // RNE
    uint_t h = (uint_t)__builtin_bit_cast(unsigned short, hf);
    uint_t s = (h >> 8) & 0x80u;
    uint_t r = h & 0x7fffu;
    if (r < 0x2400u) return (uchar_t)0;   // |v| < 2^-6 -> 0
    if (r > 0x5F40u) r = 0x5F00u;         // clamp to 448
    uint_t u = r - 0x2000u;
    uint_t m = (u + 0x3fu + ((u >> 7) & 1u)) >> 7;  // RNE to 3-bit mantissa
    return (uchar_t)(s | m);
}

// ---- CSR build -------------------------------------------------------------
constexpr int SCHUNK = 4096;

__global__ __launch_bounds__(256) void k_scan_part(const int* __restrict__ deg,
                                                   int* __restrict__ bsum, int n) {
    int t = threadIdx.x;
    int base = blockIdx.x * SCHUNK + t * 16;
    int s = 0;
#pragma unroll
    for (int j = 0; j < 16; ++j) {
        int i = base + j;
        if (i < n) s += deg[i];
    }
#pragma unroll
    for (int d = 1; d < 64; d <<= 1) s += __shfl_xor(s, d);
    __shared__ int wt[4];
    if ((t & 63) == 0) wt[t >> 6] = s;
    __syncthreads();
    if (t == 0) bsum[blockIdx.x] = wt[0] + wt[1] + wt[2] + wt[3];
}

__global__ __launch_bounds__(64) void k_scan_bsum(const int* __restrict__ bsum,
                                                  int* __restrict__ boff,
                                                  int* __restrict__ off_n, int nb) {
    int lane = threadIdx.x;
    int carry = 0;
    for (int base = 0; base < nb; base += 64) {
        int t = base + lane;
        int v = (t < nb) ? bsum[t] : 0;
        int x = v;
#pragma unroll
        for (int d = 1; d < 64; d <<= 1) {
            int y = __shfl_up(x, d);
            if (lane >= d) x += y;
        }
        if (t < nb) boff[t] = carry + x - v;
        carry += __shfl(x, 63);
    }
    if (lane == 0) *off_n = carry;
}

__global__ __launch_bounds__(256) void k_scan_apply(const int* __restrict__ deg,
                                                    const int* __restrict__ boff,
                                                    int* __restrict__ off, int n) {
    int t = threadIdx.x;
    int lane = t & 63, wid = t >> 6;
    int base = blockIdx.x * SCHUNK + t * 16;
    int v[16];
    int s = 0;
#pragma unroll
    for (int j = 0; j < 16; ++j) {
        int i = base + j;
        v[j] = (i < n) ? deg[i] : 0;
        s += v[j];
    }
    int x = s;
#pragma unroll
    for (int d = 1; d < 64; d <<= 1) {
        int y = __shfl_up(x, d);
        if (lane >= d) x += y;
    }
    __shared__ int wtot[4];
    if (lane == 63) wtot[wid] = x;
    __syncthreads();
    int woff = 0;
    for (int wj = 0; wj < wid; ++wj) woff += wtot[wj];
    int run = boff[blockIdx.x] + woff + x - s;
#pragma unroll
    for (int j = 0; j < 16; ++j) {
        int i = base + j;
        if (i < n) off[i] = run;
        run += v[j];
    }
}

__global__ __launch_bounds__(256) void k_scatter(const int* __restrict__ ei,
                                                 const int* __restrict__ off,
                                                 int* __restrict__ cur,
                                                 int* __restrict__ csr, int E) {
    int e = blockIdx.x * 256 + threadIdx.x;
    if (e < E) {
        int d = ei[E + e];
        int s = ei[e];
        int p = atomicAdd(&cur[d], 1);
        csr[off[d] + p] = s;
    }
}

// ---- fused: degree count | x->bf16+fp8 | weights->bf16 transposed ----------
__global__ __launch_bounds__(256) void k_deg_prep(const int* __restrict__ ei,
                                                  int* __restrict__ deg, int E, int eb,
                                                  const float* __restrict__ x,
                                                  ushort_t* __restrict__ xb,
                                                  uchar_t* __restrict__ x8,
                                                  int total2, int nb_cvt,
                                                  const float* __restrict__ Wl0,
                                                  const float* __restrict__ Wr0,
                                                  const float* __restrict__ Wl1,
                                                  const float* __restrict__ Wr1,
                                                  const float* __restrict__ Wl2,
                                                  const float* __restrict__ Wr2,
                                                  ushort_t* __restrict__ wts) {
    int b = blockIdx.x;
    if (b < eb) {
        int e = b * 256 + threadIdx.x;
        if (e < E) atomicAdd(&deg[ei[E + e]], 1);
        return;
    }
    b -= eb;
    if (b < nb_cvt) {
        int i = b * 256 + threadIdx.x;
        if (i >= total2) return;
        float2 v = *(const float2*)&x[(size_t)i * 2];
        uint_t p = (uint_t)f2bf(v.x) | ((uint_t)f2bf(v.y) << 16);
        *(uint_t*)&xb[(size_t)i * 2] = p;
        ushort_t q = (ushort_t)((uint_t)f2e4m3(v.x) | ((uint_t)f2e4m3(v.y) << 8));
        *(ushort_t*)&x8[(size_t)i * 2] = q;
        return;
    }
    int id = (b - nb_cvt) * 256 + threadIdx.x;
    if (id >= 81920) return;
    const float* W;
    int rel, nout, base;
    if (id < 65536) {
        int m = id >> 14;
        rel = id & 16383;
        nout = 128;
        base = m << 14;
        W = (m == 0) ? Wl0 : (m == 1) ? Wr0 : (m == 2) ? Wl1 : Wr1;
    } else {
        int m = (id - 65536) >> 13;
        rel = (id - 65536) & 8191;
        nout = 64;
        base = 65536 + (m << 13);
        W = (m == 0) ? Wl2 : Wr2;
    }
    int c = rel >> 7;
    int k = rel & 127;
    wts[base + rel] = f2bf(W[(size_t)k * nout + c]);
}

// ---- dual GEMM: fragment-major LDS B, 2 strips/wave, one col-half/block ----
// out[n][128] = X1@W1 + X2@W2 + bias. Each B ds_read feeds both strips'
// MFMAs. EPI: 2 -> relu, bf16 + fp8 out (layer 0); 1 -> bf16 out + BN stats.
template <int EPI>
__global__ __launch_bounds__(256, 3) void k_dgemm(const ushort_t* __restrict__ X1,
                                                  const ushort_t* __restrict__ W1,
                                                  const ushort_t* __restrict__ X2,
                                                  const ushort_t* __restrict__ W2,
                                                  const float* __restrict__ bias,
                                                  ushort_t* __restrict__ outp,
                                                  uchar_t* __restrict__ out8,
                                                  float* __restrict__ stats, int n) {
    constexpr int K = 128, NOUT = 128;
    __shared__ ushort_t Bs[2048 * 8];  // 32 KB, fragment-major
    __shared__ float sred[256];

    const int t = threadIdx.x;
    const int lane = t & 63;
    const int r16 = lane & 15, kb = lane >> 4;
    const int half = blockIdx.x & 1;
    const int colbase = half * 64;
    const int w = t >> 6;
    const int sA = (blockIdx.x >> 1) * 8 + w * 2;  // this wave's strip pair
    const int sB = sA + 1;

    if (EPI == 1) sred[t] = 0.f;

    // 1) issue W staging loads (8 ushort8)
    ushort8 wreg[8];
#pragma unroll
    for (int u = 0; u < 8; ++u) {
        int slot = u * 256 + t;
        int mat = slot >> 10;
        int rem = slot & 1023;
        int fnks = rem >> 6;
        int l = rem & 63;
        int fn = fnks >> 2, ks = fnks & 3;
        const ushort_t* Wm = mat ? W2 : W1;
        wreg[u] = *(const ushort8*)&Wm[(size_t)(colbase + fn * 16 + (l & 15)) * K +
                                       ks * 32 + (l >> 4) * 8];
    }
    // 2) issue A loads for both strips (16 ushort8)
    const int rowA = sA * 16 + r16, rowB = sB * 16 + r16;
    const bool okA = rowA < n, okB = rowB < n;
    const size_t xoA = (size_t)rowA * K + kb * 8;
    const size_t xoB = (size_t)rowB * K + kb * 8;
    short8 a1A[4], a2A[4], a1B[4], a2B[4];
#pragma unroll
    for (int ks = 0; ks < 4; ++ks)
        a1A[ks] = okA ? *(const short8*)&X1[xoA + ks * 32] : (short8)0;
#pragma unroll
    for (int ks = 0; ks < 4; ++ks)
        a2A[ks] = okA ? *(const short8*)&X2[xoA + ks * 32] : (short8)0;
#pragma unroll
    for (int ks = 0; ks < 4; ++ks)
        a1B[ks] = okB ? *(const short8*)&X1[xoB + ks * 32] : (short8)0;
#pragma unroll
    for (int ks = 0; ks < 4; ++ks)
        a2B[ks] = okB ? *(const short8*)&X2[xoB + ks * 32] : (short8)0;
    // 3) land staging
#pragma unroll
    for (int u = 0; u < 8; ++u) {
        int slot = u * 256 + t;
        *(ushort8*)&Bs[(size_t)slot * 8] = wreg[u];
    }
    __syncthreads();

    f32x4 accA[4] = {(f32x4)0.f, (f32x4)0.f, (f32x4)0.f, (f32x4)0.f};
    f32x4 accB[4] = {(f32x4)0.f, (f32x4)0.f, (f32x4)0.f, (f32x4)0.f};
#pragma unroll
    for (int ks = 0; ks < 4; ++ks)
#pragma unroll
        for (int fn = 0; fn < 4; ++fn) {
            short8 b = *(const short8*)&Bs[((fn * 4 + ks) * 64 + lane) * 8];
            accA[fn] = __builtin_amdgcn_mfma_f32_16x16x32_bf16(a1A[ks], b, accA[fn], 0, 0, 0);
            accB[fn] = __builtin_amdgcn_mfma_f32_16x16x32_bf16(a1B[ks], b, accB[fn], 0, 0, 0);
        }
#pragma unroll
    for (int ks = 0; ks < 4; ++ks)
#pragma unroll
        for (int fn = 0; fn < 4; ++fn) {
            short8 b = *(const short8*)&Bs[((16 + fn * 4 + ks) * 64 + lane) * 8];
            accA[fn] = __builtin_amdgcn_mfma_f32_16x16x32_bf16(a2A[ks], b, accA[fn], 0, 0, 0);
            accB[fn] = __builtin_amdgcn_mfma_f32_16x16x32_bf16(a2B[ks], b, accB[fn], 0, 0, 0);
        }

    float bcol[4];
#pragma unroll
    for (int fn = 0; fn < 4; ++fn) bcol[fn] = bias[colbase + fn * 16 + r16];

    float ssum[4] = {0.f, 0.f, 0.f, 0.f}, qsum[4] = {0.f, 0.f, 0.f, 0.f};

    // epilogue strip A
    {
        const int rb = sA * 16 + kb * 4;
#pragma unroll
        for (int r = 0; r < 4; ++r) {
            int row = rb + r;
            if (row >= n) continue;
#pragma unroll
            for (int fn = 0; fn < 4; ++fn) {
                int col = colbase + fn * 16 + r16;
                float v = accA[fn][r] + bcol[fn];
                if constexpr (EPI == 2) {
                    v = fmaxf(v, 0.f);
                    outp[(size_t)row * NOUT + col] = f2bf(v);
                    out8[(size_t)row * NOUT + col] = f2e4m3(v);
                } else {
                    outp[(size_t)row * NOUT + col] = f2bf(v);
                    ssum[fn] += v;
                    qsum[fn] += v * v;
                }
            }
        }
    }
    // epilogue strip B
    {
        const int rb = sB * 16 + kb * 4;
#pragma unroll
        for (int r = 0; r < 4; ++r) {
            int row = rb + r;
            if (row >= n) continue;
#pragma unroll
            for (int fn = 0; fn < 4; ++fn) {
                int col = colbase + fn * 16 + r16;
                float v = accB[fn][r] + bcol[fn];
                if constexpr (EPI == 2) {
                    v = fmaxf(v, 0.f);
                    outp[(size_t)row * NOUT + col] = f2bf(v);
                    out8[(size_t)row * NOUT + col] = f2e4m3(v);
                } else {
                    outp[(size_t)row * NOUT + col] = f2bf(v);
                    ssum[fn] += v;
                    qsum[fn] += v * v;
                }
            }
        }
    }

    if constexpr (EPI == 1) {
        // reduce over kb groups (lane bits 4-5), LDS-accumulate, one global
        // atomic per thread (R13-proven: ~zero marginal cost)
#pragma unroll
        for (int fn = 0; fn < 4; ++fn) {
            ssum[fn] += __shfl_xor(ssum[fn], 16);
            ssum[fn] += __shfl_xor(ssum[fn], 32);
            qsum[fn] += __shfl_xor(qsum[fn], 16);
            qsum[fn] += __shfl_xor(qsum[fn], 32);
        }
        if (kb == 0) {
#pragma unroll
            for (int fn = 0; fn < 4; ++fn) {
                int col = colbase + fn * 16 + r16;
                atomicAdd(&sred[col], ssum[fn]);
                atomicAdd(&sred[128 + col], qsum[fn]);
            }
        }
        __syncthreads();
        atomicAdd(&stats[t], sred[t]);
    }
}

// ---- layer-2 GEMM: fragment-major LDS (both mats), 4 strips per block ------
// A64 = H@Wl2 (bf16), Tb = H@Wr2 + b2 (bf16).
__global__ __launch_bounds__(256, 4) void k_cgemm(const ushort_t* __restrict__ H,
                                                  const ushort_t* __restrict__ WL,
                                                  const ushort_t* __restrict__ WR,
                                                  const float* __restrict__ b2,
                                                  ushort_t* __restrict__ A64,
                                                  ushort_t* __restrict__ Tb, int n) {
    constexpr int K = 128;
    __shared__ ushort_t Bs[2048 * 8];  // 32 KB

    const int t = threadIdx.x;
    const int lane = t & 63;
    const int r16 = lane & 15, kb = lane >> 4;
    const int strip = blockIdx.x * 4 + (t >> 6);

    ushort8 wreg[8];
#pragma unroll
    for (int u = 0; u < 8; ++u) {
        int slot = u * 256 + t;
        int mat = slot >> 10;
        int rem = slot & 1023;
        int fnks = rem >> 6;
        int l = rem & 63;
        int fn = fnks >> 2, ks = fnks & 3;
        const ushort_t* Wm = mat ? WR : WL;
        wreg[u] = *(const ushort8*)&Wm[(size_t)(fn * 16 + (l & 15)) * K +
                                       ks * 32 + (l >> 4) * 8];
    }
    const int arow = strip * 16 + r16;
    const bool rok = (arow < n);
    const size_t xo = (size_t)arow * K + kb * 8;
    short8 a[4];
#pragma unroll
    for (int ks = 0; ks < 4; ++ks)
        a[ks] = rok ? *(const short8*)&H[xo + ks * 32] : (short8)0;
#pragma unroll
    for (int u = 0; u < 8; ++u) {
        int slot = u * 256 + t;
        *(ushort8*)&Bs[(size_t)slot * 8] = wreg[u];
    }
    __syncthreads();

    f32x4 aL[4] = {(f32x4)0.f, (f32x4)0.f, (f32x4)0.f, (f32x4)0.f};
    f32x4 aR[4] = {(f32x4)0.f, (f32x4)0.f, (f32x4)0.f, (f32x4)0.f};
#pragma unroll
    for (int ks = 0; ks < 4; ++ks)
#pragma unroll
        for (int fn = 0; fn < 4; ++fn) {
            short8 bl = *(const short8*)&Bs[((fn * 4 + ks) * 64 + lane) * 8];
            short8 br = *(const short8*)&Bs[((16 + fn * 4 + ks) * 64 + lane) * 8];
            aL[fn] = __builtin_amdgcn_mfma_f32_16x16x32_bf16(a[ks], bl, aL[fn], 0, 0, 0);
            aR[fn] = __builtin_amdgcn_mfma_f32_16x16x32_bf16(a[ks], br, aR[fn], 0, 0, 0);
        }

    float bcol[4];
#pragma unroll
    for (int fn = 0; fn < 4; ++fn) bcol[fn] = b2[fn * 16 + r16];

    const int rb = strip * 16 + kb * 4;
#pragma unroll
    for (int r = 0; r < 4; ++r) {
        int row = rb + r;
        if (row >= n) continue;
#pragma unroll
        for (int fn = 0; fn < 4; ++fn) {
            int col = fn * 16 + r16;
            A64[(size_t)row * 64 + col] = f2bf(aL[fn][r]);
            Tb[(size_t)row * 64 + col] = f2bf(aR[fn][r] + bcol[fn]);
        }
    }
}

// ---- segment mean over CSR, fp8 in -> bf16 out. 8 lanes/node, 16 ch/lane ---
__global__ __launch_bounds__(256) void k_segmean8(const uchar_t* __restrict__ U8,
                                                  const int* __restrict__ off,
                                                  const int* __restrict__ srcs,
                                                  ushort_t* __restrict__ out, int n) {
    int node = blockIdx.x * 32 + (threadIdx.x >> 3);
    int sub = threadIdx.x & 7;
    if (node >= n) return;
    int beg = off[node], end = off[node + 1];
    half2v aE0 = (half2v)0, aE1 = (half2v)0, aE2 = (half2v)0, aE3 = (half2v)0;
    half2v aO0 = (half2v)0, aO1 = (half2v)0, aO2 = (half2v)0, aO3 = (half2v)0;

#define DEC(dw, AE, AO)                                                           \
    {                                                                             \
        uint_t xe = (dw)&0x00ff00ffu;                                             \
        uint_t xo = ((dw) >> 8) & 0x00ff00ffu;                                    \
        uint_t he = ((xe & 0x00800080u) << 8) |                                   \
                    (((xe & 0x007f007fu) << 7) + 0x20002000u);                    \
        uint_t ho = ((xo & 0x00800080u) << 8) |                                   \
                    (((xo & 0x007f007fu) << 7) + 0x20002000u);                    \
        AE += __builtin_bit_cast(half2v, he);                                     \
        AO += __builtin_bit_cast(half2v, ho);                                     \
    }

    auto addrow = [&](int sidx) {
        uint4 v = *(const uint4*)&U8[(size_t)sidx * 128 + sub * 16];
        DEC(v.x, aE0, aO0)
        DEC(v.y, aE1, aO1)
        DEC(v.z, aE2, aO2)
        DEC(v.w, aE3, aO3)
    };
#undef DEC

    int i = beg;
    for (; i + 8 <= end; i += 8) {
        int sv[8];
#pragma unroll
        for (int u = 0; u < 8; ++u) sv[u] = srcs[i + u];
#pragma unroll
        for (int u = 0; u < 8; ++u) addrow(sv[u]);
    }
    for (; i < end; ++i) addrow(srcs[i]);

    int d = end - beg;
    float inv = 1.f / (float)(d > 1 ? d : 1);
    ushort8 o0, o1;
#define PACK(AE, AO, O, IDX)                     \
    O[IDX] = f2bf((float)AE[0] * inv);           \
    O[IDX + 1] = f2bf((float)AO[0] * inv);       \
    O[IDX + 2] = f2bf((float)AE[1] * inv);       \
    O[IDX + 3] = f2bf((float)AO[1] * inv);
    PACK(aE0, aO0, o0, 0)
    PACK(aE1, aO1, o0, 4)
    PACK(aE2, aO2, o1, 0)
    PACK(aE3, aO3, o1, 4)
#undef PACK
    *(ushort8*)&out[(size_t)node * 128 + sub * 16] = o0;
    *(ushort8*)&out[(size_t)node * 128 + sub * 16 + 8] = o1;
}

// ---- fused 64-d segmean + log_softmax: out = lsm(segmean(A64) + Tb) --------
__global__ __launch_bounds__(256) void k_segmean_lsm(const ushort_t* __restrict__ A64,
                                                     const int* __restrict__ off,
                                                     const int* __restrict__ srcs,
                                                     const ushort_t* __restrict__ Tb,
                                                     float* __restrict__ out, int n) {
    int node = blockIdx.x * 32 + (threadIdx.x >> 3);
    int sub = threadIdx.x & 7;
    if (node >= n) return;
    int beg = off[node], end = off[node + 1];
    float a[8];
#pragma unroll
    for (int j = 0; j < 8; ++j) a[j] = 0.f;
    int i = beg;
    for (; i + 8 <= end; i += 8) {
        int sv[8];
#pragma unroll
        for (int u = 0; u < 8; ++u) sv[u] = srcs[i + u];
#pragma unroll
        for (int u = 0; u < 8; ++u) {
            ushort8 v = *(const ushort8*)&A64[(size_t)sv[u] * 64 + sub * 8];
#pragma unroll
            for (int j = 0; j < 8; ++j) a[j] += bf2f((ushort_t)v[j]);
        }
    }
    for (; i < end; ++i) {
        ushort8 v = *(const ushort8*)&A64[(size_t)srcs[i] * 64 + sub * 8];
#pragma unroll
        for (int j = 0; j < 8; ++j) a[j] += bf2f((ushort_t)v[j]);
    }
    int d = end - beg;
    float inv = 1.f / (float)(d > 1 ? d : 1);
    ushort8 tv = *(const ushort8*)&Tb[(size_t)node * 64 + sub * 8];
    float vv[8];
#pragma unroll
    for (int j = 0; j < 8; ++j) vv[j] = a[j] * inv + bf2f((ushort_t)tv[j]);
    float m = vv[0];
#pragma unroll
    for (int j = 1; j < 8; ++j) m = fmaxf(m, vv[j]);
#pragma unroll
    for (int dd = 1; dd < 8; dd <<= 1) m = fmaxf(m, __shfl_xor(m, dd));
    float e = 0.f;
#pragma unroll
    for (int j = 0; j < 8; ++j) e += expf(vv[j] - m);
#pragma unroll
    for (int dd = 1; dd < 8; dd <<= 1) e += __shfl_xor(e, dd);
    float lg = m + logf(e);
    f32x4 o0, o1;
#pragma unroll
    for (int j = 0; j < 4; ++j) {
        o0[j] = vv[j] - lg;
        o1[j] = vv[4 + j] - lg;
    }
    *(f32x4*)&out[(size_t)node * 64 + sub * 8] = o0;
    *(f32x4*)&out[(size_t)node * 64 + sub * 8 + 4] = o1;
}

// ---- BN apply + relu + residual (xb bf16), Pb bf16 -> H bf16 ---------------
__global__ __launch_bounds__(256) void k_bnapply(const ushort_t* __restrict__ P,
                                                 const ushort_t* __restrict__ Xb,
                                                 const float* __restrict__ stats,
                                                 const float* __restrict__ gamma,
                                                 const float* __restrict__ beta,
                                                 ushort_t* __restrict__ H, int n) {
    int i = blockIdx.x * 256 + threadIdx.x;  // one thread = 2 channels
    if (i >= n * 64) return;
    int nd = i >> 6;
    int c = (i & 63) << 1;
    float inv_n = 1.f / (float)n;
    float mu0 = stats[c] * inv_n, mu1 = stats[c + 1] * inv_n;
    float v0 = stats[128 + c] * inv_n - mu0 * mu0;
    float v1 = stats[128 + c + 1] * inv_n - mu1 * mu1;
    float s0 = rsqrtf(v0 + WS_EPS) * gamma[c];
    float s1 = rsqrtf(v1 + WS_EPS) * gamma[c + 1];
    uint_t pv = *(const uint_t*)&P[(size_t)nd * 128 + c];
    uint_t xv = *(const uint_t*)&Xb[(size_t)nd * 128 + c];
    float p0 = __uint_as_float(pv << 16);
    float p1 = __uint_as_float(pv & 0xffff0000u);
    float x0 = __uint_as_float(xv << 16);
    float x1 = __uint_as_float(xv & 0xffff0000u);
    float h0 = fmaxf((p0 - mu0) * s0 + beta[c], 0.f) + x0;
    float h1 = fmaxf((p1 - mu1) * s1 + beta[c + 1], 0.f) + x1;
    uint_t pk = (uint_t)f2bf(h0) | ((uint_t)f2bf(h1) << 16);
    *(uint_t*)&H[(size_t)nd * 128 + c] = pk;
}

// ---------------------------------------------------------------------------
extern "C" void kernel_launch(void* const* d_in, const int* in_sizes, int n_in,
                              void* d_out, int out_size, void* d_ws, size_t ws_size,
                              hipStream_t stream) {
    const float* x     = (const float*)d_in[0];
    const int*   ei    = (const int*)d_in[1];
    const float* Wl0   = (const float*)d_in[2];
    const float* Wr0   = (const float*)d_in[3];
    const float* b0    = (const float*)d_in[4];
    const float* Wl1   = (const float*)d_in[5];
    const float* Wr1   = (const float*)d_in[6];
    const float* b1    = (const float*)d_in[7];
    const float* Wl2   = (const float*)d_in[8];
    const float* Wr2   = (const float*)d_in[9];
    const float* b2    = (const float*)d_in[10];
    const float* gamma = (const float*)d_in[11];
    const float* beta  = (const float*)d_in[12];

    const int n = in_sizes[0] / 128;
    const int E = in_sizes[1] / 2;
    const int nb_scan = (n + SCHUNK - 1) / SCHUNK;

    char* w = (char*)d_ws;
    auto alloc = [&](size_t bytes) -> void* {
        void* p = (void*)w;
        w += (bytes + 255) & ~(size_t)255;
        return p;
    };
    int*      deg   = (int*)alloc((size_t)n * 4);
    int*      cur   = (int*)alloc((size_t)n * 4);
    float*    stats = (float*)alloc(256 * 4);
    size_t    zbytes = (size_t)((char*)w - (char*)deg);
    int*      off   = (int*)alloc(((size_t)n + 1) * 4);
    int*      csr   = (int*)alloc((size_t)E * 4);
    int*      bsum  = (int*)alloc(256 * 4);
    int*      boff  = (int*)alloc(256 * 4);
    ushort_t* wts   = (ushort_t*)alloc((size_t)81920 * 2);
    ushort_t* xb    = (ushort_t*)alloc((size_t)n * 128 * 2);
    uchar_t*  x8    = (uchar_t*)alloc((size_t)n * 128);
    ushort_t* H     = (ushort_t*)alloc((size_t)n * 128 * 2);
    uchar_t*  H8    = (uchar_t*)alloc((size_t)n * 128);
    ushort_t* Pb    = (ushort_t*)alloc((size_t)n * 128 * 2);
    ushort_t* M     = (ushort_t*)alloc((size_t)n * 128 * 2);
    ushort_t* A64   = (ushort_t*)alloc((size_t)n * 64 * 2);
    ushort_t* Tb    = (ushort_t*)alloc((size_t)n * 64 * 2);

    ushort_t* WtL0 = wts;
    ushort_t* WtR0 = wts + 16384;
    ushort_t* WtL1 = wts + 32768;
    ushort_t* WtR1 = wts + 49152;
    ushort_t* WtL2 = wts + 65536;
    ushort_t* WtR2 = wts + 73728;

    hipMemsetAsync(deg, 0, zbytes, stream);

    const int eb = (E + 255) / 256;
    const int nb_cvt = (n * 64 + 255) / 256;
    k_deg_prep<<<eb + nb_cvt + 320, 256, 0, stream>>>(ei, deg, E, eb, x, xb, x8,
                                                      n * 64, nb_cvt,
                                                      Wl0, Wr0, Wl1, Wr1, Wl2, Wr2, wts);
    k_scan_part<<<nb_scan, 256, 0, stream>>>(deg, bsum, n);
    k_scan_bsum<<<1, 64, 0, stream>>>(bsum, boff, off + n, nb_scan);
    k_scan_apply<<<nb_scan, 256, 0, stream>>>(deg, boff, off, n);
    k_scatter<<<(E + 255) / 256, 256, 0, stream>>>(ei, off, cur, csr, E);

    const int strips = (n + 15) / 16;
    const int gb_d = 2 * ((strips + 7) / 8);  // halves x strip-octets
    const int gb_c = (strips + 3) / 4;
    const int smb = (n + 31) / 32;

    // layer 0: M = segmean(x8); H,H8 = relu(xb@Wr0 + M@Wl0 + b0)
    k_segmean8<<<smb, 256, 0, stream>>>(x8, off, csr, M, n);
    k_dgemm<2><<<gb_d, 256, 0, stream>>>(xb, WtR0, M, WtL0, b0, H, H8, nullptr, n);

    // layer 1: M = segmean(H8); Pb = H@Wr1 + M@Wl1 + b1 (+BN stats); BN apply
    k_segmean8<<<smb, 256, 0, stream>>>(H8, off, csr, M, n);
    k_dgemm<1><<<gb_d, 256, 0, stream>>>(H, WtR1, M, WtL1, b1, Pb, nullptr, stats, n);
    k_bnapply<<<(n * 64 + 255) / 256, 256, 0, stream>>>(Pb, xb, stats, gamma, beta, H, n);

    // layer 2: {A64 = H@Wl2, Tb = H@Wr2 + b2}; out = lsm(segmean(A64) + Tb)
    k_cgemm<<<gb_c, 256, 0, stream>>>(H, WtL2, WtR2, b2, A64, Tb, n);
    k_segmean_lsm<<<smb, 256, 0, stream>>>(A64, off, csr, Tb, (float*)d_out, n);
}

// Round 17
// 205.197 us; speedup vs baseline: 1.4977x; 1.0962x over previous
//
#include <hip/hip_runtime.h>
#include <hip/hip_bf16.h>

// ---------------------------------------------------------------------------
// GraphSAGE 3-layer forward. bf16 MFMA GEMMs (f32 accum).
// R17:
//  - dgemm strip-QUAD: 4 strips/wave, each B ds_read feeds 4 MFMAs, W-staging
//    traffic halved again (392 blocks x 32KB). __launch_bounds__(256,2).
//  - BN apply fused into cgemm: H never materialized; cgemm loads Pb+xb and
//    computes relu(p*s+t)+x in registers (s,t staged in 1KB LDS, broadcast
//    reads). Saves a kernel + 25.6MB round-trip.
//  - GEMM LDS fragment-major (R15): ds_read_b128 = lane*16+imm, conflict-free.
//   layer0: H,H8 = relu(x@Wr0 + segmean8(x8)@Wl0 + b0)
//   layer1: Pb = H@Wr1 + segmean8(H8)@Wl1 + b1 (+f32 BN stats in epilogue)
//   layer2: {A64 = BN'(Pb,xb)@Wl2, Tb = BN'(Pb,xb)@Wr2 + b2};
//           out = log_softmax(segmean(A64) + Tb)
// ---------------------------------------------------------------------------

#define WS_EPS 1e-5f

typedef unsigned short ushort_t;
typedef unsigned int uint_t;
typedef unsigned char uchar_t;
typedef ushort_t ushort8 __attribute__((ext_vector_type(8)));
typedef short short8 __attribute__((ext_vector_type(8)));
typedef float f32x4 __attribute__((ext_vector_type(4)));
typedef _Float16 half2v __attribute__((ext_vector_type(2)));

__device__ __forceinline__ float bf2f(ushort_t u) {
    return __uint_as_float(((uint_t)u) << 16);
}
__device__ __forceinline__ ushort_t f2bf(float f) {
    uint_t u = __float_as_uint(f);
    u = (u + 0x7fffu + ((u >> 16) & 1u)) >> 16;  // RNE
    return (ushort_t)u;
}
// f32 -> OCP e4m3fn with flush-to-zero of subnormals (decode = pure bit ops)
__device__ __forceinline__ uchar_t f2e4m3(float f) {
    _Float16 hf = (_Float16)f;  // RNE
    uint_t h = (uint_t)__builtin_bit_cast(unsigned short, hf);
    uint_t s = (h >> 8) & 0x80u;
    uint_t r = h & 0x7fffu;
    if (r < 0x2400u) return (uchar_t)0;   // |v| < 2^-6 -> 0
    if (r > 0x5F40u) r = 0x5F00u;         // clamp to 448
    uint_t u = r - 0x2000u;
    uint_t m = (u + 0x3fu + ((u >> 7) & 1u)) >> 7;  // RNE to 3-bit mantissa
    return (uchar_t)(s | m);
}

// ---- CSR build -------------------------------------------------------------
constexpr int SCHUNK = 4096;

__global__ __launch_bounds__(256) void k_scan_part(const int* __restrict__ deg,
                                                   int* __restrict__ bsum, int n) {
    int t = threadIdx.x;
    int base = blockIdx.x * SCHUNK + t * 16;
    int s = 0;
#pragma unroll
    for (int j = 0; j < 16; ++j) {
        int i = base + j;
        if (i < n) s += deg[i];
    }
#pragma unroll
    for (int d = 1; d < 64; d <<= 1) s += __shfl_xor(s, d);
    __shared__ int wt[4];
    if ((t & 63) == 0) wt[t >> 6] = s;
    __syncthreads();
    if (t == 0) bsum[blockIdx.x] = wt[0] + wt[1] + wt[2] + wt[3];
}

__global__ __launch_bounds__(64) void k_scan_bsum(const int* __restrict__ bsum,
                                                  int* __restrict__ boff,
                                                  int* __restrict__ off_n, int nb) {
    int lane = threadIdx.x;
    int carry = 0;
    for (int base = 0; base < nb; base += 64) {
        int t = base + lane;
        int v = (t < nb) ? bsum[t] : 0;
        int x = v;
#pragma unroll
        for (int d = 1; d < 64; d <<= 1) {
            int y = __shfl_up(x, d);
            if (lane >= d) x += y;
        }
        if (t < nb) boff[t] = carry + x - v;
        carry += __shfl(x, 63);
    }
    if (lane == 0) *off_n = carry;
}

__global__ __launch_bounds__(256) void k_scan_apply(const int* __restrict__ deg,
                                                    const int* __restrict__ boff,
                                                    int* __restrict__ off, int n) {
    int t = threadIdx.x;
    int lane = t & 63, wid = t >> 6;
    int base = blockIdx.x * SCHUNK + t * 16;
    int v[16];
    int s = 0;
#pragma unroll
    for (int j = 0; j < 16; ++j) {
        int i = base + j;
        v[j] = (i < n) ? deg[i] : 0;
        s += v[j];
    }
    int x = s;
#pragma unroll
    for (int d = 1; d < 64; d <<= 1) {
        int y = __shfl_up(x, d);
        if (lane >= d) x += y;
    }
    __shared__ int wtot[4];
    if (lane == 63) wtot[wid] = x;
    __syncthreads();
    int woff = 0;
    for (int wj = 0; wj < wid; ++wj) woff += wtot[wj];
    int run = boff[blockIdx.x] + woff + x - s;
#pragma unroll
    for (int j = 0; j < 16; ++j) {
        int i = base + j;
        if (i < n) off[i] = run;
        run += v[j];
    }
}

__global__ __launch_bounds__(256) void k_scatter(const int* __restrict__ ei,
                                                 const int* __restrict__ off,
                                                 int* __restrict__ cur,
                                                 int* __restrict__ csr, int E) {
    int e = blockIdx.x * 256 + threadIdx.x;
    if (e < E) {
        int d = ei[E + e];
        int s = ei[e];
        int p = atomicAdd(&cur[d], 1);
        csr[off[d] + p] = s;
    }
}

// ---- fused: degree count | x->bf16+fp8 | weights->bf16 transposed ----------
__global__ __launch_bounds__(256) void k_deg_prep(const int* __restrict__ ei,
                                                  int* __restrict__ deg, int E, int eb,
                                                  const float* __restrict__ x,
                                                  ushort_t* __restrict__ xb,
                                                  uchar_t* __restrict__ x8,
                                                  int total2, int nb_cvt,
                                                  const float* __restrict__ Wl0,
                                                  const float* __restrict__ Wr0,
                                                  const float* __restrict__ Wl1,
                                                  const float* __restrict__ Wr1,
                                                  const float* __restrict__ Wl2,
                                                  const float* __restrict__ Wr2,
                                                  ushort_t* __restrict__ wts) {
    int b = blockIdx.x;
    if (b < eb) {
        int e = b * 256 + threadIdx.x;
        if (e < E) atomicAdd(&deg[ei[E + e]], 1);
        return;
    }
    b -= eb;
    if (b < nb_cvt) {
        int i = b * 256 + threadIdx.x;
        if (i >= total2) return;
        float2 v = *(const float2*)&x[(size_t)i * 2];
        uint_t p = (uint_t)f2bf(v.x) | ((uint_t)f2bf(v.y) << 16);
        *(uint_t*)&xb[(size_t)i * 2] = p;
        ushort_t q = (ushort_t)((uint_t)f2e4m3(v.x) | ((uint_t)f2e4m3(v.y) << 8));
        *(ushort_t*)&x8[(size_t)i * 2] = q;
        return;
    }
    int id = (b - nb_cvt) * 256 + threadIdx.x;
    if (id >= 81920) return;
    const float* W;
    int rel, nout, base;
    if (id < 65536) {
        int m = id >> 14;
        rel = id & 16383;
        nout = 128;
        base = m << 14;
        W = (m == 0) ? Wl0 : (m == 1) ? Wr0 : (m == 2) ? Wl1 : Wr1;
    } else {
        int m = (id - 65536) >> 13;
        rel = (id - 65536) & 8191;
        nout = 64;
        base = 65536 + (m << 13);
        W = (m == 0) ? Wl2 : Wr2;
    }
    int c = rel >> 7;
    int k = rel & 127;
    wts[base + rel] = f2bf(W[(size_t)k * nout + c]);
}

// ---- dual GEMM: fragment-major LDS B, 4 strips/wave, one col-half/block ----
// out[n][128] = X1@W1 + X2@W2 + bias. Each B ds_read feeds 4 strips' MFMAs.
// EPI: 2 -> relu, bf16 + fp8 out (layer 0); 1 -> bf16 out + BN stats.
#define DG_LOADA(A1, A2, SS)                                                   \
    {                                                                          \
        int row_ = (SS)*16 + r16;                                              \
        bool ok_ = row_ < n;                                                   \
        size_t xo_ = (size_t)row_ * K + kb * 8;                                \
        _Pragma("unroll") for (int ks = 0; ks < 4; ++ks)                       \
            A1[ks] = ok_ ? *(const short8*)&X1[xo_ + ks * 32] : (short8)0;     \
        _Pragma("unroll") for (int ks = 0; ks < 4; ++ks)                       \
            A2[ks] = ok_ ? *(const short8*)&X2[xo_ + ks * 32] : (short8)0;     \
    }

#define DG_EPI(ACC, SS)                                                        \
    {                                                                          \
        const int rb_ = (SS)*16 + kb * 4;                                      \
        _Pragma("unroll") for (int r = 0; r < 4; ++r) {                        \
            int row_ = rb_ + r;                                                \
            if (row_ < n) {                                                    \
                _Pragma("unroll") for (int fn = 0; fn < 4; ++fn) {             \
                    int col_ = colbase + fn * 16 + r16;                        \
                    float v_ = ACC[fn][r] + bcol[fn];                          \
                    if (EPI == 2) {                                            \
                        v_ = fmaxf(v_, 0.f);                                   \
                        outp[(size_t)row_ * NOUT + col_] = f2bf(v_);           \
                        out8[(size_t)row_ * NOUT + col_] = f2e4m3(v_);         \
                    } else {                                                   \
                        outp[(size_t)row_ * NOUT + col_] = f2bf(v_);           \
                        ssum[fn] += v_;                                        \
                        qsum[fn] += v_ * v_;                                   \
                    }                                                          \
                }                                                              \
            }                                                                  \
        }                                                                      \
    }

template <int EPI>
__global__ __launch_bounds__(256, 2) void k_dgemm(const ushort_t* __restrict__ X1,
                                                  const ushort_t* __restrict__ W1,
                                                  const ushort_t* __restrict__ X2,
                                                  const ushort_t* __restrict__ W2,
                                                  const float* __restrict__ bias,
                                                  ushort_t* __restrict__ outp,
                                                  uchar_t* __restrict__ out8,
                                                  float* __restrict__ stats, int n) {
    constexpr int K = 128, NOUT = 128;
    __shared__ ushort_t Bs[2048 * 8];  // 32 KB, fragment-major
    __shared__ float sred[256];

    const int t = threadIdx.x;
    const int lane = t & 63;
    const int r16 = lane & 15, kb = lane >> 4;
    const int half = blockIdx.x & 1;
    const int colbase = half * 64;
    const int w = t >> 6;
    const int sA = (blockIdx.x >> 1) * 16 + w * 4;  // wave's strip quad
    const int sB = sA + 1, sC = sA + 2, sD = sA + 3;

    if (EPI == 1) sred[t] = 0.f;

    // 1) issue W staging loads (8 ushort8)
    ushort8 wreg[8];
#pragma unroll
    for (int u = 0; u < 8; ++u) {
        int slot = u * 256 + t;
        int mat = slot >> 10;
        int rem = slot & 1023;
        int fnks = rem >> 6;
        int l = rem & 63;
        int fn = fnks >> 2, ks = fnks & 3;
        const ushort_t* Wm = mat ? W2 : W1;
        wreg[u] = *(const ushort8*)&Wm[(size_t)(colbase + fn * 16 + (l & 15)) * K +
                                       ks * 32 + (l >> 4) * 8];
    }
    // 2) issue A loads for 4 strips (32 ushort8)
    short8 a1A[4], a2A[4], a1B[4], a2B[4], a1C[4], a2C[4], a1D[4], a2D[4];
    DG_LOADA(a1A, a2A, sA)
    DG_LOADA(a1B, a2B, sB)
    DG_LOADA(a1C, a2C, sC)
    DG_LOADA(a1D, a2D, sD)
    // 3) land staging
#pragma unroll
    for (int u = 0; u < 8; ++u) {
        int slot = u * 256 + t;
        *(ushort8*)&Bs[(size_t)slot * 8] = wreg[u];
    }
    __syncthreads();

    f32x4 accA[4] = {(f32x4)0.f, (f32x4)0.f, (f32x4)0.f, (f32x4)0.f};
    f32x4 accB[4] = {(f32x4)0.f, (f32x4)0.f, (f32x4)0.f, (f32x4)0.f};
    f32x4 accC[4] = {(f32x4)0.f, (f32x4)0.f, (f32x4)0.f, (f32x4)0.f};
    f32x4 accD[4] = {(f32x4)0.f, (f32x4)0.f, (f32x4)0.f, (f32x4)0.f};
#pragma unroll
    for (int ks = 0; ks < 4; ++ks)
#pragma unroll
        for (int fn = 0; fn < 4; ++fn) {
            short8 b = *(const short8*)&Bs[((fn * 4 + ks) * 64 + lane) * 8];
            accA[fn] = __builtin_amdgcn_mfma_f32_16x16x32_bf16(a1A[ks], b, accA[fn], 0, 0, 0);
            accB[fn] = __builtin_amdgcn_mfma_f32_16x16x32_bf16(a1B[ks], b, accB[fn], 0, 0, 0);
            accC[fn] = __builtin_amdgcn_mfma_f32_16x16x32_bf16(a1C[ks], b, accC[fn], 0, 0, 0);
            accD[fn] = __builtin_amdgcn_mfma_f32_16x16x32_bf16(a1D[ks], b, accD[fn], 0, 0, 0);
        }
#pragma unroll
    for (int ks = 0; ks < 4; ++ks)
#pragma unroll
        for (int fn = 0; fn < 4; ++fn) {
            short8 b = *(const short8*)&Bs[((16 + fn * 4 + ks) * 64 + lane) * 8];
            accA[fn] = __builtin_amdgcn_mfma_f32_16x16x32_bf16(a2A[ks], b, accA[fn], 0, 0, 0);
            accB[fn] = __builtin_amdgcn_mfma_f32_16x16x32_bf16(a2B[ks], b, accB[fn], 0, 0, 0);
            accC[fn] = __builtin_amdgcn_mfma_f32_16x16x32_bf16(a2C[ks], b, accC[fn], 0, 0, 0);
            accD[fn] = __builtin_amdgcn_mfma_f32_16x16x32_bf16(a2D[ks], b, accD[fn], 0, 0, 0);
        }

    float bcol[4];
#pragma unroll
    for (int fn = 0; fn < 4; ++fn) bcol[fn] = bias[colbase + fn * 16 + r16];

    float ssum[4] = {0.f, 0.f, 0.f, 0.f}, qsum[4] = {0.f, 0.f, 0.f, 0.f};
    DG_EPI(accA, sA)
    DG_EPI(accB, sB)
    DG_EPI(accC, sC)
    DG_EPI(accD, sD)

    if constexpr (EPI == 1) {
#pragma unroll
        for (int fn = 0; fn < 4; ++fn) {
            ssum[fn] += __shfl_xor(ssum[fn], 16);
            ssum[fn] += __shfl_xor(ssum[fn], 32);
            qsum[fn] += __shfl_xor(qsum[fn], 16);
            qsum[fn] += __shfl_xor(qsum[fn], 32);
        }
        if (kb == 0) {
#pragma unroll
            for (int fn = 0; fn < 4; ++fn) {
                int col = colbase + fn * 16 + r16;
                atomicAdd(&sred[col], ssum[fn]);
                atomicAdd(&sred[128 + col], qsum[fn]);
            }
        }
        __syncthreads();
        atomicAdd(&stats[t], sred[t]);
    }
}

// ---- layer-2 GEMM with fused BN/relu/residual ------------------------------
// A-operand built in registers: h = relu(Pb*s + t) + xb; s,t staged in LDS
// (16-lane broadcast reads). A64 = h@Wl2 (bf16), Tb = h@Wr2 + b2 (bf16).
__global__ __launch_bounds__(256, 4) void k_cgemm_bn(const ushort_t* __restrict__ Pb,
                                                     const ushort_t* __restrict__ Xb,
                                                     const float* __restrict__ stats,
                                                     const float* __restrict__ gamma,
                                                     const float* __restrict__ beta,
                                                     const ushort_t* __restrict__ WL,
                                                     const ushort_t* __restrict__ WR,
                                                     const float* __restrict__ b2,
                                                     ushort_t* __restrict__ A64,
                                                     ushort_t* __restrict__ Tb, int n) {
    constexpr int K = 128;
    __shared__ ushort_t Bs[2048 * 8];  // 32 KB
    __shared__ float st[256];          // s[128] | t[128]

    const int t = threadIdx.x;
    const int lane = t & 63;
    const int r16 = lane & 15, kb = lane >> 4;
    const int strip = blockIdx.x * 4 + (t >> 6);

    ushort8 wreg[8];
#pragma unroll
    for (int u = 0; u < 8; ++u) {
        int slot = u * 256 + t;
        int mat = slot >> 10;
        int rem = slot & 1023;
        int fnks = rem >> 6;
        int l = rem & 63;
        int fn = fnks >> 2, ks = fnks & 3;
        const ushort_t* Wm = mat ? WR : WL;
        wreg[u] = *(const ushort8*)&Wm[(size_t)(fn * 16 + (l & 15)) * K +
                                       ks * 32 + (l >> 4) * 8];
    }
    if (t < 128) {
        float inv_n = 1.f / (float)n;
        float mu = stats[t] * inv_n;
        float var = stats[128 + t] * inv_n - mu * mu;
        float s = rsqrtf(var + WS_EPS) * gamma[t];
        st[t] = s;
        st[128 + t] = beta[t] - mu * s;
    }
    const int arow = strip * 16 + r16;
    const bool rok = (arow < n);
    const size_t xo = (size_t)arow * K + kb * 8;
    short8 pv[4], xv[4];
#pragma unroll
    for (int ks = 0; ks < 4; ++ks)
        pv[ks] = rok ? *(const short8*)&Pb[xo + ks * 32] : (short8)0;
#pragma unroll
    for (int ks = 0; ks < 4; ++ks)
        xv[ks] = rok ? *(const short8*)&Xb[xo + ks * 32] : (short8)0;
#pragma unroll
    for (int u = 0; u < 8; ++u) {
        int slot = u * 256 + t;
        *(ushort8*)&Bs[(size_t)slot * 8] = wreg[u];
    }
    __syncthreads();

    // build BN'd A-fragments
    short8 a[4];
#pragma unroll
    for (int ks = 0; ks < 4; ++ks) {
#pragma unroll
        for (int j = 0; j < 8; ++j) {
            int c = ks * 32 + kb * 8 + j;
            float pp = bf2f((ushort_t)pv[ks][j]);
            float xx = bf2f((ushort_t)xv[ks][j]);
            float h = fmaxf(pp * st[c] + st[128 + c], 0.f) + xx;
            a[ks][j] = (short)f2bf(h);
        }
    }

    f32x4 aL[4] = {(f32x4)0.f, (f32x4)0.f, (f32x4)0.f, (f32x4)0.f};
    f32x4 aR[4] = {(f32x4)0.f, (f32x4)0.f, (f32x4)0.f, (f32x4)0.f};
#pragma unroll
    for (int ks = 0; ks < 4; ++ks)
#pragma unroll
        for (int fn = 0; fn < 4; ++fn) {
            short8 bl = *(const short8*)&Bs[((fn * 4 + ks) * 64 + lane) * 8];
            short8 br = *(const short8*)&Bs[((16 + fn * 4 + ks) * 64 + lane) * 8];
            aL[fn] = __builtin_amdgcn_mfma_f32_16x16x32_bf16(a[ks], bl, aL[fn], 0, 0, 0);
            aR[fn] = __builtin_amdgcn_mfma_f32_16x16x32_bf16(a[ks], br, aR[fn], 0, 0, 0);
        }

    float bcol[4];
#pragma unroll
    for (int fn = 0; fn < 4; ++fn) bcol[fn] = b2[fn * 16 + r16];

    const int rb = strip * 16 + kb * 4;
#pragma unroll
    for (int r = 0; r < 4; ++r) {
        int row = rb + r;
        if (row >= n) continue;
#pragma unroll
        for (int fn = 0; fn < 4; ++fn) {
            int col = fn * 16 + r16;
            A64[(size_t)row * 64 + col] = f2bf(aL[fn][r]);
            Tb[(size_t)row * 64 + col] = f2bf(aR[fn][r] + bcol[fn]);
        }
    }
}

// ---- segment mean over CSR, fp8 in -> bf16 out. 8 lanes/node, 16 ch/lane ---
__global__ __launch_bounds__(256) void k_segmean8(const uchar_t* __restrict__ U8,
                                                  const int* __restrict__ off,
                                                  const int* __restrict__ srcs,
                                                  ushort_t* __restrict__ out, int n) {
    int node = blockIdx.x * 32 + (threadIdx.x >> 3);
    int sub = threadIdx.x & 7;
    if (node >= n) return;
    int beg = off[node], end = off[node + 1];
    half2v aE0 = (half2v)0, aE1 = (half2v)0, aE2 = (half2v)0, aE3 = (half2v)0;
    half2v aO0 = (half2v)0, aO1 = (half2v)0, aO2 = (half2v)0, aO3 = (half2v)0;

#define DEC(dw, AE, AO)                                                           \
    {                                                                             \
        uint_t xe = (dw)&0x00ff00ffu;                                             \
        uint_t xo = ((dw) >> 8) & 0x00ff00ffu;                                    \
        uint_t he = ((xe & 0x00800080u) << 8) |                                   \
                    (((xe & 0x007f007fu) << 7) + 0x20002000u);                    \
        uint_t ho = ((xo & 0x00800080u) << 8) |                                   \
                    (((xo & 0x007f007fu) << 7) + 0x20002000u);                    \
        AE += __builtin_bit_cast(half2v, he);                                     \
        AO += __builtin_bit_cast(half2v, ho);                                     \
    }

    auto addrow = [&](int sidx) {
        uint4 v = *(const uint4*)&U8[(size_t)sidx * 128 + sub * 16];
        DEC(v.x, aE0, aO0)
        DEC(v.y, aE1, aO1)
        DEC(v.z, aE2, aO2)
        DEC(v.w, aE3, aO3)
    };
#undef DEC

    int i = beg;
    for (; i + 8 <= end; i += 8) {
        int sv[8];
#pragma unroll
        for (int u = 0; u < 8; ++u) sv[u] = srcs[i + u];
#pragma unroll
        for (int u = 0; u < 8; ++u) addrow(sv[u]);
    }
    for (; i < end; ++i) addrow(srcs[i]);

    int d = end - beg;
    float inv = 1.f / (float)(d > 1 ? d : 1);
    ushort8 o0, o1;
#define PACK(AE, AO, O, IDX)                     \
    O[IDX] = f2bf((float)AE[0] * inv);           \
    O[IDX + 1] = f2bf((float)AO[0] * inv);       \
    O[IDX + 2] = f2bf((float)AE[1] * inv);       \
    O[IDX + 3] = f2bf((float)AO[1] * inv);
    PACK(aE0, aO0, o0, 0)
    PACK(aE1, aO1, o0, 4)
    PACK(aE2, aO2, o1, 0)
    PACK(aE3, aO3, o1, 4)
#undef PACK
    *(ushort8*)&out[(size_t)node * 128 + sub * 16] = o0;
    *(ushort8*)&out[(size_t)node * 128 + sub * 16 + 8] = o1;
}

// ---- fused 64-d segmean + log_softmax: out = lsm(segmean(A64) + Tb) --------
__global__ __launch_bounds__(256) void k_segmean_lsm(const ushort_t* __restrict__ A64,
                                                     const int* __restrict__ off,
                                                     const int* __restrict__ srcs,
                                                     const ushort_t* __restrict__ Tb,
                                                     float* __restrict__ out, int n) {
    int node = blockIdx.x * 32 + (threadIdx.x >> 3);
    int sub = threadIdx.x & 7;
    if (node >= n) return;
    int beg = off[node], end = off[node + 1];
    float a[8];
#pragma unroll
    for (int j = 0; j < 8; ++j) a[j] = 0.f;
    int i = beg;
    for (; i + 8 <= end; i += 8) {
        int sv[8];
#pragma unroll
        for (int u = 0; u < 8; ++u) sv[u] = srcs[i + u];
#pragma unroll
        for (int u = 0; u < 8; ++u) {
            ushort8 v = *(const ushort8*)&A64[(size_t)sv[u] * 64 + sub * 8];
#pragma unroll
            for (int j = 0; j < 8; ++j) a[j] += bf2f((ushort_t)v[j]);
        }
    }
    for (; i < end; ++i) {
        ushort8 v = *(const ushort8*)&A64[(size_t)srcs[i] * 64 + sub * 8];
#pragma unroll
        for (int j = 0; j < 8; ++j) a[j] += bf2f((ushort_t)v[j]);
    }
    int d = end - beg;
    float inv = 1.f / (float)(d > 1 ? d : 1);
    ushort8 tv = *(const ushort8*)&Tb[(size_t)node * 64 + sub * 8];
    float vv[8];
#pragma unroll
    for (int j = 0; j < 8; ++j) vv[j] = a[j] * inv + bf2f((ushort_t)tv[j]);
    float m = vv[0];
#pragma unroll
    for (int j = 1; j < 8; ++j) m = fmaxf(m, vv[j]);
#pragma unroll
    for (int dd = 1; dd < 8; dd <<= 1) m = fmaxf(m, __shfl_xor(m, dd));
    float e = 0.f;
#pragma unroll
    for (int j = 0; j < 8; ++j) e += expf(vv[j] - m);
#pragma unroll
    for (int dd = 1; dd < 8; dd <<= 1) e += __shfl_xor(e, dd);
    float lg = m + logf(e);
    f32x4 o0, o1;
#pragma unroll
    for (int j = 0; j < 4; ++j) {
        o0[j] = vv[j] - lg;
        o1[j] = vv[4 + j] - lg;
    }
    *(f32x4*)&out[(size_t)node * 64 + sub * 8] = o0;
    *(f32x4*)&out[(size_t)node * 64 + sub * 8 + 4] = o1;
}

// ---------------------------------------------------------------------------
extern "C" void kernel_launch(void* const* d_in, const int* in_sizes, int n_in,
                              void* d_out, int out_size, void* d_ws, size_t ws_size,
                              hipStream_t stream) {
    const float* x     = (const float*)d_in[0];
    const int*   ei    = (const int*)d_in[1];
    const float* Wl0   = (const float*)d_in[2];
    const float* Wr0   = (const float*)d_in[3];
    const float* b0    = (const float*)d_in[4];
    const float* Wl1   = (const float*)d_in[5];
    const float* Wr1   = (const float*)d_in[6];
    const float* b1    = (const float*)d_in[7];
    const float* Wl2   = (const float*)d_in[8];
    const float* Wr2   = (const float*)d_in[9];
    const float* b2    = (const float*)d_in[10];
    const float* gamma = (const float*)d_in[11];
    const float* beta  = (const float*)d_in[12];

    const int n = in_sizes[0] / 128;
    const int E = in_sizes[1] / 2;
    const int nb_scan = (n + SCHUNK - 1) / SCHUNK;

    char* w = (char*)d_ws;
    auto alloc = [&](size_t bytes) -> void* {
        void* p = (void*)w;
        w += (bytes + 255) & ~(size_t)255;
        return p;
    };
    int*      deg   = (int*)alloc((size_t)n * 4);
    int*      cur   = (int*)alloc((size_t)n * 4);
    float*    stats = (float*)alloc(256 * 4);
    size_t    zbytes = (size_t)((char*)w - (char*)deg);
    int*      off   = (int*)alloc(((size_t)n + 1) * 4);
    int*      csr   = (int*)alloc((size_t)E * 4);
    int*      bsum  = (int*)alloc(256 * 4);
    int*      boff  = (int*)alloc(256 * 4);
    ushort_t* wts   = (ushort_t*)alloc((size_t)81920 * 2);
    ushort_t* xb    = (ushort_t*)alloc((size_t)n * 128 * 2);
    uchar_t*  x8    = (uchar_t*)alloc((size_t)n * 128);
    ushort_t* H     = (ushort_t*)alloc((size_t)n * 128 * 2);
    uchar_t*  H8    = (uchar_t*)alloc((size_t)n * 128);
    ushort_t* Pb    = (ushort_t*)alloc((size_t)n * 128 * 2);
    ushort_t* M     = (ushort_t*)alloc((size_t)n * 128 * 2);
    ushort_t* A64   = (ushort_t*)alloc((size_t)n * 64 * 2);
    ushort_t* Tb    = (ushort_t*)alloc((size_t)n * 64 * 2);

    ushort_t* WtL0 = wts;
    ushort_t* WtR0 = wts + 16384;
    ushort_t* WtL1 = wts + 32768;
    ushort_t* WtR1 = wts + 49152;
    ushort_t* WtL2 = wts + 65536;
    ushort_t* WtR2 = wts + 73728;

    hipMemsetAsync(deg, 0, zbytes, stream);

    const int eb = (E + 255) / 256;
    const int nb_cvt = (n * 64 + 255) / 256;
    k_deg_prep<<<eb + nb_cvt + 320, 256, 0, stream>>>(ei, deg, E, eb, x, xb, x8,
                                                      n * 64, nb_cvt,
                                                      Wl0, Wr0, Wl1, Wr1, Wl2, Wr2, wts);
    k_scan_part<<<nb_scan, 256, 0, stream>>>(deg, bsum, n);
    k_scan_bsum<<<1, 64, 0, stream>>>(bsum, boff, off + n, nb_scan);
    k_scan_apply<<<nb_scan, 256, 0, stream>>>(deg, boff, off, n);
    k_scatter<<<(E + 255) / 256, 256, 0, stream>>>(ei, off, cur, csr, E);

    const int strips = (n + 15) / 16;
    const int gb_d = 2 * ((strips + 15) / 16);  // halves x strip-16-groups
    const int gb_c = (strips + 3) / 4;
    const int smb = (n + 31) / 32;

    // layer 0: M = segmean(x8); H,H8 = relu(xb@Wr0 + M@Wl0 + b0)
    k_segmean8<<<smb, 256, 0, stream>>>(x8, off, csr, M, n);
    k_dgemm<2><<<gb_d, 256, 0, stream>>>(xb, WtR0, M, WtL0, b0, H, H8, nullptr, n);

    // layer 1: M = segmean(H8); Pb = H@Wr1 + M@Wl1 + b1 (+BN stats)
    k_segmean8<<<smb, 256, 0, stream>>>(H8, off, csr, M, n);
    k_dgemm<1><<<gb_d, 256, 0, stream>>>(H, WtR1, M, WtL1, b1, Pb, nullptr, stats, n);

    // layer 2 (BN fused): {A64 = h@Wl2, Tb = h@Wr2 + b2} with
    // h = relu(BN(Pb)) + xb built in registers; out = lsm(segmean(A64) + Tb)
    k_cgemm_bn<<<gb_c, 256, 0, stream>>>(Pb, xb, stats, gamma, beta,
                                         WtL2, WtR2, b2, A64, Tb, n);
    k_segmean_lsm<<<smb, 256, 0, stream>>>(A64, off, csr, Tb, (float*)d_out, n);
}